// Round 1
// baseline (423.516 us; speedup 1.0000x reference)
//
#include <hip/hip_runtime.h>
#include <cstddef>
#include <cstdint>

constexpr int Bb = 16, Ss = 512, Dd = 256, Hh = 8, HDd = 32, Ff = 682, Fp = 688;
constexpr float EPSf = 1.1920928955078125e-07f;

// ---------------- embed + rmsnorm ----------------
__global__ __launch_bounds__(256) void k_embed_norm(
    const float* __restrict__ emb, const float* __restrict__ pos,
    const int* __restrict__ tok, const float* __restrict__ w,
    float* __restrict__ h, float* __restrict__ x)
{
  const int row = blockIdx.x;            // b*S + s
  const int s = row & (Ss - 1);
  const int tid = threadIdx.x;           // one per d (256)
  const int t = tok[row];
  float v = emb[(size_t)t * Dd + tid] + pos[(size_t)s * Dd + tid];
  float ss = v * v;
  #pragma unroll
  for (int off = 32; off > 0; off >>= 1) ss += __shfl_down(ss, off);
  __shared__ float red[4];
  if ((tid & 63) == 0) red[tid >> 6] = ss;
  __syncthreads();
  const float tot = red[0] + red[1] + red[2] + red[3];
  const float r = rsqrtf(tot * (1.0f / Dd) + EPSf);
  const size_t o = (size_t)row * Dd + tid;
  h[o] = v;
  x[o] = v * r * w[tid];
}

// ---------------- residual add + rmsnorm ----------------
__global__ __launch_bounds__(256) void k_add_norm(
    const float* __restrict__ a, const float* __restrict__ hbuf,
    const float* __restrict__ w, float* __restrict__ x2)
{
  const int row = blockIdx.x;
  const int tid = threadIdx.x;
  const size_t off = (size_t)row * Dd + tid;
  const float v = a[off] + hbuf[off];
  float ss = v * v;
  #pragma unroll
  for (int o = 32; o > 0; o >>= 1) ss += __shfl_down(ss, o);
  __shared__ float red[4];
  if ((tid & 63) == 0) red[tid >> 6] = ss;
  __syncthreads();
  const float tot = red[0] + red[1] + red[2] + red[3];
  const float r = rsqrtf(tot * (1.0f / Dd) + EPSf);
  x2[off] = v * r * w[tid];
}

// ---------------- generic f32 NT GEMM: C[m,n] = sum_k A[m,k]*W[n,k] + bias[n] (+resid) ----
template<bool AVEC, bool WVEC>
__global__ __launch_bounds__(256) void k_gemm(
    const float* __restrict__ A, int lda,
    const float* __restrict__ W,
    const float* __restrict__ bias,
    const float* __restrict__ resid,   // nullable, ld = ldc
    float* __restrict__ C, int ldc,
    int M, int N, int K)
{
  __shared__ float As[16][68];   // [k][m], pad 4 -> 16B-aligned float4 rows, no 4-way conflicts
  __shared__ float Bs[16][68];   // [k][n]
  const int tid = threadIdx.x;
  const int m0 = blockIdx.x * 64;
  const int n0 = blockIdx.y * 64;
  const int ty = tid >> 4, tx = tid & 15;
  const int sm = tid >> 2;                 // staging row 0..63
  const int sk = (tid & 3) << 2;           // staging k offset 0/4/8/12
  float acc[4][4] = {{0.f}};

  for (int k0 = 0; k0 < K; k0 += 16) {
    const int gk = k0 + sk;
    {
      const float* ap = A + (size_t)(m0 + sm) * lda + gk;
      float a0, a1, a2, a3;
      if (AVEC && gk + 4 <= K) {
        const float4 t4 = *(const float4*)ap;
        a0 = t4.x; a1 = t4.y; a2 = t4.z; a3 = t4.w;
      } else {
        a0 = (gk + 0 < K) ? ap[0] : 0.f;
        a1 = (gk + 1 < K) ? ap[1] : 0.f;
        a2 = (gk + 2 < K) ? ap[2] : 0.f;
        a3 = (gk + 3 < K) ? ap[3] : 0.f;
      }
      As[sk + 0][sm] = a0; As[sk + 1][sm] = a1;
      As[sk + 2][sm] = a2; As[sk + 3][sm] = a3;

      const int gn = n0 + sm;
      float b0 = 0.f, b1 = 0.f, b2 = 0.f, b3 = 0.f;
      if (gn < N) {
        const float* wp = W + (size_t)gn * K + gk;
        if (WVEC && gk + 4 <= K) {
          const float4 t4 = *(const float4*)wp;
          b0 = t4.x; b1 = t4.y; b2 = t4.z; b3 = t4.w;
        } else {
          b0 = (gk + 0 < K) ? wp[0] : 0.f;
          b1 = (gk + 1 < K) ? wp[1] : 0.f;
          b2 = (gk + 2 < K) ? wp[2] : 0.f;
          b3 = (gk + 3 < K) ? wp[3] : 0.f;
        }
      }
      Bs[sk + 0][sm] = b0; Bs[sk + 1][sm] = b1;
      Bs[sk + 2][sm] = b2; Bs[sk + 3][sm] = b3;
    }
    __syncthreads();
    #pragma unroll
    for (int kk = 0; kk < 16; kk++) {
      const float4 a4 = *(const float4*)&As[kk][ty << 2];
      const float4 b4 = *(const float4*)&Bs[kk][tx << 2];
      const float av[4] = {a4.x, a4.y, a4.z, a4.w};
      const float bw[4] = {b4.x, b4.y, b4.z, b4.w};
      #pragma unroll
      for (int i = 0; i < 4; i++)
        #pragma unroll
        for (int j = 0; j < 4; j++)
          acc[i][j] = fmaf(av[i], bw[j], acc[i][j]);
    }
    __syncthreads();
  }

  #pragma unroll
  for (int i = 0; i < 4; i++) {
    const int mrow = m0 + (ty << 2) + i;
    #pragma unroll
    for (int j = 0; j < 4; j++) {
      const int n = n0 + (tx << 2) + j;
      if (n < N) {
        float cv = acc[i][j] + bias[n];
        if (resid) cv += resid[(size_t)mrow * ldc + n];
        C[(size_t)mrow * ldc + n] = cv;
      }
    }
  }
}

// ---------------- attention (rope fused, online softmax) ----------------
// grid: (qtile=2, H, B); 256 threads, one q-row per thread
__global__ __launch_bounds__(256) void k_attn(
    const float* __restrict__ q, const float* __restrict__ k,
    const float* __restrict__ v, const float* __restrict__ cost,
    const float* __restrict__ sint, float* __restrict__ o)
{
  __shared__ float lk[256][32];
  __shared__ float lv[256][32];
  const int tid = threadIdx.x;
  const int qt = blockIdx.x, hh = blockIdx.y, bb = blockIdx.z;
  const int s2 = qt * 256 + tid;
  const size_t bh = ((size_t)bb * Hh + hh) * Ss;

  float qr[32];
  {
    const float* qrow = q + (bh + s2) * HDd;
    #pragma unroll
    for (int i = 0; i < 16; i++) {
      const float c = cost[s2 * HDd + 2 * i];
      const float sn = sint[s2 * HDd + 2 * i];
      const float xe = qrow[2 * i], xo = qrow[2 * i + 1];
      qr[2 * i]     = xe * c - xo * sn;
      qr[2 * i + 1] = xe * sn + xo * c;
    }
  }

  float m = -3.0e38f, l = 0.f;
  float acc[32];
  #pragma unroll
  for (int i = 0; i < 32; i++) acc[i] = 0.f;
  const float scale = 0.17677669529663687f;  // 1/sqrt(32)

  for (int t0 = 0; t0 <= qt * 256; t0 += 256) {
    __syncthreads();
    {
      const int t = t0 + tid;
      const float* krow = k + ((size_t)bb * Ss + t) * HDd;
      #pragma unroll
      for (int i = 0; i < 16; i++) {
        const float c = cost[t * HDd + 2 * i];
        const float sn = sint[t * HDd + 2 * i];
        const float xe = krow[2 * i], xo = krow[2 * i + 1];
        lk[tid][2 * i]     = xe * c - xo * sn;
        lk[tid][2 * i + 1] = xe * sn + xo * c;
      }
      const float* vrow = v + (bh + t) * HDd;
      #pragma unroll
      for (int i = 0; i < 8; i++) {
        const float4 t4 = *(const float4*)(vrow + 4 * i);
        lv[tid][4 * i] = t4.x; lv[tid][4 * i + 1] = t4.y;
        lv[tid][4 * i + 2] = t4.z; lv[tid][4 * i + 3] = t4.w;
      }
    }
    __syncthreads();
    int tmax = s2 - t0; if (tmax > 255) tmax = 255;
    for (int tt = 0; tt <= tmax; tt++) {
      float sd = 0.f;
      #pragma unroll
      for (int j = 0; j < 32; j++) sd = fmaf(qr[j], lk[tt][j], sd);
      sd *= scale;
      const float nm = fmaxf(m, sd);
      const float corr = __expf(m - nm);
      const float p = __expf(sd - nm);
      l = l * corr + p;
      #pragma unroll
      for (int j = 0; j < 32; j++) acc[j] = fmaf(acc[j], corr, p * lv[tt][j]);
      m = nm;
    }
  }
  const float inv = 1.f / l;
  float* orow = o + (bh + s2) * HDd;
  #pragma unroll
  for (int j = 0; j < 32; j++) orow[j] = acc[j] * inv;
}

// ---------------- silu(g)*up, in place into g ----------------
__global__ __launch_bounds__(256) void k_silu(
    float* __restrict__ g, const float* __restrict__ up)
{
  const int row = blockIdx.x;
  const int tid = threadIdx.x;
  for (int f = tid; f < Ff; f += 256) {
    const size_t off = (size_t)row * Fp + f;
    const float gg = g[off];
    const float uu = up[off];
    g[off] = gg * uu / (1.f + __expf(-gg));
  }
}

extern "C" void kernel_launch(void* const* d_in, const int* in_sizes, int n_in,
                              void* d_out, int out_size, void* d_ws, size_t ws_size,
                              hipStream_t stream)
{
  const float* emb     = (const float*)d_in[0];
  const float* pos_emb = (const float*)d_in[1];
  const float* attn_w  = (const float*)d_in[2];
  const float* wq      = (const float*)d_in[3];
  const float* bq      = (const float*)d_in[4];
  const float* wk      = (const float*)d_in[5];
  const float* bk      = (const float*)d_in[6];
  const float* wv      = (const float*)d_in[7];
  const float* bv      = (const float*)d_in[8];
  const float* cos_t   = (const float*)d_in[9];
  const float* sin_t   = (const float*)d_in[10];
  const float* ffn_w   = (const float*)d_in[11];
  const float* w_gate  = (const float*)d_in[12];
  const float* b_gate  = (const float*)d_in[13];
  const float* w_up    = (const float*)d_in[14];
  const float* b_up    = (const float*)d_in[15];
  const float* w_down  = (const float*)d_in[16];
  const float* b_down  = (const float*)d_in[17];
  const int*   tok     = (const int*)d_in[18];
  float* out = (float*)d_out;

  float* ws = (float*)d_ws;
  const size_t NT = (size_t)Bb * Ss;        // 8192 rows
  float* h   = ws;                          // NT*D
  float* x   = h  + NT * Dd;                // NT*D
  float* q   = x  + NT * Dd;                // NT*D   (flat == (B,H,S,HD))
  float* kk  = q  + NT * Dd;                // NT*HD
  float* v   = kk + NT * HDd;               // NT*D   (flat == (B,H,S,HD))
  float* o   = v  + NT * Dd;                // NT*D
  float* x2  = o  + NT * Dd;                // NT*D
  float* g   = x2 + NT * Dd;                // NT*Fp
  float* up  = g  + NT * Fp;                // NT*Fp

  k_embed_norm<<<dim3(NT), 256, 0, stream>>>(emb, pos_emb, tok, attn_w, h, x);

  k_gemm<true, true><<<dim3(NT / 64, 4), 256, 0, stream>>>(
      x, Dd, wq, bq, nullptr, q, Dd, (int)NT, Dd, Dd);
  k_gemm<true, true><<<dim3(NT / 64, 1), 256, 0, stream>>>(
      x, Dd, wk, bk, nullptr, kk, HDd, (int)NT, HDd, Dd);
  k_gemm<true, true><<<dim3(NT / 64, 4), 256, 0, stream>>>(
      x, Dd, wv, bv, nullptr, v, Dd, (int)NT, Dd, Dd);

  k_attn<<<dim3(2, Hh, Bb), 256, 0, stream>>>(q, kk, v, cos_t, sin_t, o);

  k_add_norm<<<dim3(NT), 256, 0, stream>>>(o, h, ffn_w, x2);

  k_gemm<true, true><<<dim3(NT / 64, 11), 256, 0, stream>>>(
      x2, Dd, w_gate, b_gate, nullptr, g, Fp, (int)NT, Ff, Dd);
  k_gemm<true, true><<<dim3(NT / 64, 11), 256, 0, stream>>>(
      x2, Dd, w_up, b_up, nullptr, up, Fp, (int)NT, Ff, Dd);

  k_silu<<<dim3(NT), 256, 0, stream>>>(g, up);

  k_gemm<true, false><<<dim3(NT / 64, 4), 256, 0, stream>>>(
      g, Fp, w_down, b_down, x2, out, Dd, (int)NT, Dd, Ff);
}

// Round 2
// 221.963 us; speedup vs baseline: 1.9080x; 1.9080x over previous
//
#include <hip/hip_runtime.h>
#include <hip/hip_bf16.h>
#include <cstddef>
#include <cstdint>

constexpr int Bb = 16, Ss = 512, Dd = 256, Hh = 8, HDd = 32, Ff = 682;
constexpr int FKp = 704;            // padded K for down GEMM (682 -> 704 = 11*64)
constexpr float EPSf = 1.1920928955078125e-07f;

typedef short bf8v __attribute__((ext_vector_type(8)));
typedef float f4 __attribute__((ext_vector_type(4)));
using bf16 = __hip_bfloat16;

__device__ inline f4 MFMA(bf8v a, bf8v b, f4 c) {
  return __builtin_amdgcn_mfma_f32_16x16x32_bf16(a, b, c, 0, 0, 0);
}

// ---------------- embed + rmsnorm -> h(f32), x_bf(bf16) ----------------
__global__ __launch_bounds__(256) void k_embed_norm(
    const float* __restrict__ emb, const float* __restrict__ pos,
    const int* __restrict__ tok, const float* __restrict__ w,
    float* __restrict__ h, bf16* __restrict__ xb)
{
  const int row = blockIdx.x;
  const int s = row & (Ss - 1);
  const int tid = threadIdx.x;
  const int t = tok[row];
  float v = emb[(size_t)t * Dd + tid] + pos[(size_t)s * Dd + tid];
  float ss = v * v;
  #pragma unroll
  for (int off = 32; off > 0; off >>= 1) ss += __shfl_down(ss, off);
  __shared__ float red[4];
  if ((tid & 63) == 0) red[tid >> 6] = ss;
  __syncthreads();
  const float tot = red[0] + red[1] + red[2] + red[3];
  const float r = rsqrtf(tot * (1.0f / Dd) + EPSf);
  const size_t o = (size_t)row * Dd + tid;
  h[o] = v;
  xb[o] = __float2bfloat16(v * r * w[tid]);
}

// ---------------- residual add + rmsnorm -> x2(f32), x2_bf ----------------
__global__ __launch_bounds__(256) void k_add_norm(
    const float* __restrict__ a, const float* __restrict__ hbuf,
    const float* __restrict__ w, float* __restrict__ x2, bf16* __restrict__ x2b)
{
  const int row = blockIdx.x;
  const int tid = threadIdx.x;
  const size_t off = (size_t)row * Dd + tid;
  const float v = a[off] + hbuf[off];
  float ss = v * v;
  #pragma unroll
  for (int o = 32; o > 0; o >>= 1) ss += __shfl_down(ss, o);
  __shared__ float red[4];
  if ((tid & 63) == 0) red[tid >> 6] = ss;
  __syncthreads();
  const float tot = red[0] + red[1] + red[2] + red[3];
  const float r = rsqrtf(tot * (1.0f / Dd) + EPSf);
  const float xv = v * r * w[tid];
  x2[off] = xv;
  x2b[off] = __float2bfloat16(xv);
}

// ---------------- f32 -> bf16 weight convert with zero padding ----------------
__global__ __launch_bounds__(256) void k_cvt(
    const float* __restrict__ src, bf16* __restrict__ dst,
    int K, int Kp, int N, int Np)
{
  const int idx = blockIdx.x * 256 + threadIdx.x;
  if (idx >= Np * Kp) return;
  const int row = idx / Kp, col = idx - row * Kp;
  float v = (row < N && col < K) ? src[(size_t)row * K + col] : 0.f;
  dst[idx] = __float2bfloat16(v);
}

// ---------------- bf16 MFMA GEMM, NT: C[m,n] = sum_k A[m,k]*W[n,k] ----------------
__global__ __launch_bounds__(256) void k_gemm_bf16(
    const bf16* __restrict__ A, const bf16* __restrict__ W, int K,
    int mode,
    const float* __restrict__ bias0, const float* __restrict__ bias1,
    const float* __restrict__ bias2,
    const float* __restrict__ cost, const float* __restrict__ sint,
    const float* __restrict__ aux,      // mode3: g f32; mode2: x2 resid
    float* __restrict__ outf,
    bf16* __restrict__ ob0, bf16* __restrict__ ob1, bf16* __restrict__ ob2)
{
  __shared__ bf16 As[128 * 72];
  __shared__ bf16 Bs[128 * 72];
  const int tid = threadIdx.x, lane = tid & 63, wid = tid >> 6;
  const int l15 = lane & 15, lg = lane >> 4;
  const int m0 = blockIdx.x * 128, n0 = blockIdx.y * 128;
  const int wr = (wid >> 1) * 64, wc = (wid & 1) * 64;

  f4 acc[4][4];
  #pragma unroll
  for (int i = 0; i < 4; i++)
    #pragma unroll
    for (int j = 0; j < 4; j++) acc[i][j] = (f4){0.f, 0.f, 0.f, 0.f};

  for (int k0 = 0; k0 < K; k0 += 64) {
    #pragma unroll
    for (int i = 0; i < 4; i++) {
      const int c = i * 256 + tid;          // chunk 0..1023
      const int row = c >> 3, col = (c & 7) * 8;
      *(bf8v*)&As[row * 72 + col] = *(const bf8v*)&A[(size_t)(m0 + row) * K + k0 + col];
      *(bf8v*)&Bs[row * 72 + col] = *(const bf8v*)&W[(size_t)(n0 + row) * K + k0 + col];
    }
    __syncthreads();
    #pragma unroll
    for (int kk = 0; kk < 64; kk += 32) {
      bf8v af[4], bw[4];
      #pragma unroll
      for (int mi = 0; mi < 4; mi++)
        af[mi] = *(const bf8v*)&As[(wr + mi * 16 + l15) * 72 + kk + lg * 8];
      #pragma unroll
      for (int ni = 0; ni < 4; ni++)
        bw[ni] = *(const bf8v*)&Bs[(wc + ni * 16 + l15) * 72 + kk + lg * 8];
      #pragma unroll
      for (int mi = 0; mi < 4; mi++)
        #pragma unroll
        for (int ni = 0; ni < 4; ni++)
          acc[mi][ni] = MFMA(af[mi], bw[ni], acc[mi][ni]);
    }
    __syncthreads();
  }

  #pragma unroll
  for (int mi = 0; mi < 4; mi++) {
    #pragma unroll
    for (int ni = 0; ni < 4; ni++) {
      const int nbase = n0 + wc + ni * 16;       // lane-uniform fragment col base
      const int n = nbase + l15;
      #pragma unroll
      for (int r = 0; r < 4; r++) {
        const int m = m0 + wr + mi * 16 + lg * 4 + r;
        float v = acc[mi][ni][r];
        if (mode == 0) {
          if (nbase < 288) {                      // q or k region: rope
            float vb = v + (nbase < 256 ? bias0[n] : bias1[n - 256]);
            int s, hd;
            if (nbase < 256) { const int flat = ((m & 511) << 8) + n; s = (flat >> 5) & 511; hd = n & 31; }
            else             { s = m & 511; hd = n - 256; }
            const float c = cost[s * 32 + hd], sn = sint[s * 32 + hd];
            const float other = __shfl_xor(vb, 1);
            const float res = (n & 1) ? (other * sn + vb * c) : (vb * c - other * sn);
            if (nbase < 256) ob0[(size_t)m * 256 + n] = __float2bfloat16(res);
            else             ob1[(size_t)m * 32 + hd] = __float2bfloat16(res);
          } else if (n < 544) {
            ob2[(size_t)m * 256 + (n - 288)] = __float2bfloat16(v + bias2[n - 288]);
          }
        } else if (mode == 1) {
          if (n < Ff) outf[(size_t)m * Ff + n] = v + bias0[n];
        } else if (mode == 3) {
          if (n < Ff) {
            const float u = v + bias0[n];
            const float gg = aux[(size_t)m * Ff + n];
            const float sl = gg / (1.f + __expf(-gg));
            ob0[(size_t)m * FKp + n] = __float2bfloat16(sl * u);
          } else if (n < FKp) {
            ob0[(size_t)m * FKp + n] = __float2bfloat16(0.f);
          }
        } else {                                   // mode 2: down
          outf[(size_t)m * 256 + n] = v + bias0[n] + aux[(size_t)m * 256 + n];
        }
      }
    }
  }
}

// ---------------- v (B,H,S,HD) bf16 -> vt (B,H,HD,S) bf16 ----------------
__global__ __launch_bounds__(256) void k_vtrans(
    const bf16* __restrict__ v, bf16* __restrict__ vt)
{
  const int bh = blockIdx.y;
  const int s0 = blockIdx.x * 64;
  const int hd = threadIdx.x & 31, sc = threadIdx.x >> 5;   // sc 0..7
  const int s = s0 + sc * 8;
  bf16 tmp[8];
  #pragma unroll
  for (int j = 0; j < 8; j++)
    tmp[j] = v[((size_t)bh * Ss + s + j) * HDd + hd];
  *(bf8v*)&vt[(size_t)bh * (Ss * HDd) + (size_t)hd * Ss + s] = *(const bf8v*)tmp;
}

// ---------------- MFMA flash attention ----------------
__global__ __launch_bounds__(256) void k_attn_mfma(
    const bf16* __restrict__ q, const bf16* __restrict__ k,
    const bf16* __restrict__ vt, float* __restrict__ o)
{
  __shared__ bf16 Ks[64 * 40];       // [t][40 pad]
  __shared__ bf16 Vs[32 * 72];       // [hd][72 pad]  (V transposed)
  __shared__ bf16 Ps[4][16 * 72];    // per wave [q][72 pad]
  const int tid = threadIdx.x, lane = tid & 63, wid = tid >> 6;
  const int l15 = lane & 15, lg = lane >> 4;
  const int qt = blockIdx.x, hh = blockIdx.y, bb = blockIdx.z;
  const int bh = bb * Hh + hh;
  const int qbase = qt * 64 + wid * 16;
  const float scale = 0.17677669529663687f;

  const bf8v qf = *(const bf8v*)&q[((size_t)bh * Ss + qbase + l15) * HDd + lg * 8];

  f4 oacc[2];
  oacc[0] = (f4){0.f, 0.f, 0.f, 0.f};
  oacc[1] = (f4){0.f, 0.f, 0.f, 0.f};
  float mr[4] = {-3.0e38f, -3.0e38f, -3.0e38f, -3.0e38f};
  float lr[4] = {0.f, 0.f, 0.f, 0.f};

  for (int t0 = 0; t0 <= qt * 64; t0 += 64) {
    __syncthreads();
    {
      const int tr = tid >> 2, tc = (tid & 3) * 8;
      *(bf8v*)&Ks[tr * 40 + tc] =
          *(const bf8v*)&k[((size_t)bb * Ss + t0 + tr) * HDd + tc];
      const int hd = tid >> 3, c8 = (tid & 7) * 8;
      *(bf8v*)&Vs[hd * 72 + c8] =
          *(const bf8v*)&vt[(size_t)bh * (Ss * HDd) + (size_t)hd * Ss + t0 + c8];
    }
    __syncthreads();

    f4 sf[4];
    #pragma unroll
    for (int tf = 0; tf < 4; tf++) {
      const bf8v kf = *(const bf8v*)&Ks[(tf * 16 + l15) * 40 + lg * 8];
      sf[tf] = MFMA(qf, kf, (f4){0.f, 0.f, 0.f, 0.f});
    }

    const bool diag = (t0 == qt * 64);
    float pm[4] = {-3.0e38f, -3.0e38f, -3.0e38f, -3.0e38f};
    #pragma unroll
    for (int tf = 0; tf < 4; tf++)
      #pragma unroll
      for (int r = 0; r < 4; r++) {
        float sv = sf[tf][r] * scale;
        if (diag && (t0 + tf * 16 + l15 > qbase + lg * 4 + r)) sv = -3.0e38f;
        sf[tf][r] = sv;
        pm[r] = fmaxf(pm[r], sv);
      }
    #pragma unroll
    for (int r = 0; r < 4; r++) {
      #pragma unroll
      for (int x = 1; x < 16; x <<= 1) pm[r] = fmaxf(pm[r], __shfl_xor(pm[r], x));
    }
    float corr[4];
    #pragma unroll
    for (int r = 0; r < 4; r++) {
      const float nm = fmaxf(mr[r], pm[r]);
      corr[r] = __expf(mr[r] - nm);
      mr[r] = nm;
    }
    float lsum[4] = {0.f, 0.f, 0.f, 0.f};
    #pragma unroll
    for (int tf = 0; tf < 4; tf++)
      #pragma unroll
      for (int r = 0; r < 4; r++) {
        const float p = __expf(sf[tf][r] - mr[r]);
        sf[tf][r] = p;
        lsum[r] += p;
      }
    #pragma unroll
    for (int tf = 0; tf < 4; tf++)
      #pragma unroll
      for (int r = 0; r < 4; r++)
        Ps[wid][(lg * 4 + r) * 72 + tf * 16 + l15] = __float2bfloat16(sf[tf][r]);
    #pragma unroll
    for (int r = 0; r < 4; r++) {
      #pragma unroll
      for (int x = 1; x < 16; x <<= 1) lsum[r] += __shfl_xor(lsum[r], x);
      lr[r] = lr[r] * corr[r] + lsum[r];
    }
    #pragma unroll
    for (int hf = 0; hf < 2; hf++)
      #pragma unroll
      for (int r = 0; r < 4; r++) oacc[hf][r] *= corr[r];

    #pragma unroll
    for (int kt = 0; kt < 2; kt++) {
      const bf8v pa = *(const bf8v*)&Ps[wid][l15 * 72 + kt * 32 + lg * 8];
      #pragma unroll
      for (int hf = 0; hf < 2; hf++) {
        const bf8v vb = *(const bf8v*)&Vs[(hf * 16 + l15) * 72 + kt * 32 + lg * 8];
        oacc[hf] = MFMA(pa, vb, oacc[hf]);
      }
    }
  }

  #pragma unroll
  for (int hf = 0; hf < 2; hf++)
    #pragma unroll
    for (int r = 0; r < 4; r++)
      o[((size_t)bh * Ss + qbase + lg * 4 + r) * HDd + hf * 16 + l15] =
          oacc[hf][r] / lr[r];
}

extern "C" void kernel_launch(void* const* d_in, const int* in_sizes, int n_in,
                              void* d_out, int out_size, void* d_ws, size_t ws_size,
                              hipStream_t stream)
{
  const float* emb     = (const float*)d_in[0];
  const float* pos_emb = (const float*)d_in[1];
  const float* attn_w  = (const float*)d_in[2];
  const float* wq      = (const float*)d_in[3];
  const float* bq      = (const float*)d_in[4];
  const float* wk      = (const float*)d_in[5];
  const float* bk      = (const float*)d_in[6];
  const float* wv      = (const float*)d_in[7];
  const float* bv      = (const float*)d_in[8];
  const float* cos_t   = (const float*)d_in[9];
  const float* sin_t   = (const float*)d_in[10];
  const float* ffn_w   = (const float*)d_in[11];
  const float* w_gate  = (const float*)d_in[12];
  const float* b_gate  = (const float*)d_in[13];
  const float* w_up    = (const float*)d_in[14];
  const float* b_up    = (const float*)d_in[15];
  const float* w_down  = (const float*)d_in[16];
  const float* b_down  = (const float*)d_in[17];
  const int*   tok     = (const int*)d_in[18];
  float* out = (float*)d_out;

  const size_t NT = (size_t)Bb * Ss;   // 8192
  char* base = (char*)d_ws;
  size_t off = 0;
  auto alloc = [&](size_t bytes) {
    void* r = base + off;
    off = (off + bytes + 255) & ~(size_t)255;
    return r;
  };
  float* h      = (float*)alloc(NT * Dd * 4);
  bf16*  x_bf   = (bf16*)alloc(NT * Dd * 2);
  bf16*  q_bf   = (bf16*)alloc(NT * Dd * 2);
  bf16*  k_bf   = (bf16*)alloc(NT * HDd * 2);
  bf16*  v_bf   = (bf16*)alloc(NT * Dd * 2);
  bf16*  vt_bf  = (bf16*)alloc(NT * Dd * 2);
  float* o_     = (float*)alloc(NT * Dd * 4);
  float* x2     = (float*)alloc(NT * Dd * 4);
  bf16*  x2_bf  = (bf16*)alloc(NT * Dd * 2);
  float* g      = (float*)alloc(NT * (size_t)Ff * 4);
  bf16*  g_bf   = (bf16*)alloc(NT * (size_t)FKp * 2);
  bf16*  wqkv_b = (bf16*)alloc((size_t)640 * 256 * 2);
  bf16*  wgate_b= (bf16*)alloc((size_t)768 * 256 * 2);
  bf16*  wup_b  = (bf16*)alloc((size_t)768 * 256 * 2);
  bf16*  wdown_b= (bf16*)alloc((size_t)256 * FKp * 2);

  k_cvt<<<dim3(256), 256, 0, stream>>>(wq, wqkv_b, 256, 256, 256, 256);
  k_cvt<<<dim3(32), 256, 0, stream>>>(wk, wqkv_b + 256 * 256, 256, 256, 32, 32);
  k_cvt<<<dim3(352), 256, 0, stream>>>(wv, wqkv_b + 288 * 256, 256, 256, 256, 352);
  k_cvt<<<dim3(768), 256, 0, stream>>>(w_gate, wgate_b, 256, 256, 682, 768);
  k_cvt<<<dim3(768), 256, 0, stream>>>(w_up, wup_b, 256, 256, 682, 768);
  k_cvt<<<dim3(704), 256, 0, stream>>>(w_down, wdown_b, 682, FKp, 256, 256);

  k_embed_norm<<<dim3(NT), 256, 0, stream>>>(emb, pos_emb, tok, attn_w, h, x_bf);

  k_gemm_bf16<<<dim3(NT / 128, 5), 256, 0, stream>>>(
      x_bf, wqkv_b, 256, 0, bq, bk, bv, cos_t, sin_t, nullptr,
      nullptr, q_bf, k_bf, v_bf);

  k_vtrans<<<dim3(Ss / 64, Bb * Hh), 256, 0, stream>>>(v_bf, vt_bf);

  k_attn_mfma<<<dim3(Ss / 64, Hh, Bb), 256, 0, stream>>>(q_bf, k_bf, vt_bf, o_);

  k_add_norm<<<dim3(NT), 256, 0, stream>>>(o_, h, ffn_w, x2, x2_bf);

  k_gemm_bf16<<<dim3(NT / 128, 6), 256, 0, stream>>>(
      x2_bf, wgate_b, 256, 1, b_gate, nullptr, nullptr, nullptr, nullptr,
      nullptr, g, nullptr, nullptr, nullptr);

  k_gemm_bf16<<<dim3(NT / 128, 6), 256, 0, stream>>>(
      x2_bf, wup_b, 256, 3, b_up, nullptr, nullptr, nullptr, nullptr,
      g, nullptr, g_bf, nullptr, nullptr);

  k_gemm_bf16<<<dim3(NT / 128, 2), 256, 0, stream>>>(
      g_bf, wdown_b, FKp, 2, b_down, nullptr, nullptr, nullptr, nullptr,
      x2, out, nullptr, nullptr, nullptr);
}

// Round 4
// 116.527 us; speedup vs baseline: 3.6345x; 1.9048x over previous
//
#include <hip/hip_runtime.h>
#include <hip/hip_bf16.h>
#include <cstddef>
#include <cstdint>

constexpr int Bb = 16, Ss = 512, Dd = 256, Hh = 8, HDd = 32, Ff = 682;
constexpr int FKp = 704;            // padded K for down GEMM (682 -> 704 = 11*64)
constexpr float EPSf = 1.1920928955078125e-07f;

typedef short bf8v __attribute__((ext_vector_type(8)));
typedef float f4 __attribute__((ext_vector_type(4)));
using bf16 = __hip_bfloat16;

__device__ inline f4 MFMA(bf8v a, bf8v b, f4 c) {
  return __builtin_amdgcn_mfma_f32_16x16x32_bf16(a, b, c, 0, 0, 0);
}

// ---------------- embed + rmsnorm -> h(f32), x_bf(bf16) ----------------
__global__ __launch_bounds__(256) void k_embed_norm(
    const float* __restrict__ emb, const float* __restrict__ pos,
    const int* __restrict__ tok, const float* __restrict__ w,
    float* __restrict__ h, bf16* __restrict__ xb)
{
  const int row = blockIdx.x;
  const int s = row & (Ss - 1);
  const int tid = threadIdx.x;
  const int t = tok[row];
  float v = emb[(size_t)t * Dd + tid] + pos[(size_t)s * Dd + tid];
  float ss = v * v;
  #pragma unroll
  for (int off = 32; off > 0; off >>= 1) ss += __shfl_down(ss, off);
  __shared__ float red[4];
  if ((tid & 63) == 0) red[tid >> 6] = ss;
  __syncthreads();
  const float tot = red[0] + red[1] + red[2] + red[3];
  const float r = rsqrtf(tot * (1.0f / Dd) + EPSf);
  const size_t o = (size_t)row * Dd + tid;
  h[o] = v;
  xb[o] = __float2bfloat16(v * r * w[tid]);
}

// ---------------- residual add + rmsnorm -> x2(f32), x2_bf ----------------
__global__ __launch_bounds__(256) void k_add_norm(
    const float* __restrict__ a, const float* __restrict__ hbuf,
    const float* __restrict__ w, float* __restrict__ x2, bf16* __restrict__ x2b)
{
  const int row = blockIdx.x;
  const int tid = threadIdx.x;
  const size_t off = (size_t)row * Dd + tid;
  const float v = a[off] + hbuf[off];
  float ss = v * v;
  #pragma unroll
  for (int o = 32; o > 0; o >>= 1) ss += __shfl_down(ss, o);
  __shared__ float red[4];
  if ((tid & 63) == 0) red[tid >> 6] = ss;
  __syncthreads();
  const float tot = red[0] + red[1] + red[2] + red[3];
  const float r = rsqrtf(tot * (1.0f / Dd) + EPSf);
  const float xv = v * r * w[tid];
  x2[off] = xv;
  x2b[off] = __float2bfloat16(xv);
}

// ---------------- qkv weight pack: [640][256] bf16 (q 0..255, k 256..287, v 288..543, pad) ----
__global__ __launch_bounds__(256) void k_cvt_qkv(
    const float* __restrict__ wq, const float* __restrict__ wk,
    const float* __restrict__ wv, bf16* __restrict__ dst)
{
  const int idx = blockIdx.x * 256 + threadIdx.x;   // 640*256
  const int row = idx >> 8, col = idx & 255;
  float v;
  if (row < 256)      v = wq[(size_t)row * 256 + col];
  else if (row < 288) v = wk[(size_t)(row - 256) * 256 + col];
  else if (row < 544) v = wv[(size_t)(row - 288) * 256 + col];
  else                v = 0.f;
  dst[idx] = __float2bfloat16(v);
}

// ---------------- generic f32 -> bf16 weight convert with zero padding ----------------
__global__ __launch_bounds__(256) void k_cvt(
    const float* __restrict__ src, bf16* __restrict__ dst,
    int K, int Kp, int N, int Np)
{
  const int idx = blockIdx.x * 256 + threadIdx.x;
  if (idx >= Np * Kp) return;
  const int row = idx / Kp, col = idx - row * Kp;
  float v = (row < N && col < K) ? src[(size_t)row * K + col] : 0.f;
  dst[idx] = __float2bfloat16(v);
}

// ---------------- qkv GEMM: C[m,n] = sum_k x[m,k]*Wqkv[n,k], K=256, rope epilogue ----
__global__ __launch_bounds__(256) void k_qkv(
    const bf16* __restrict__ A, const bf16* __restrict__ W,
    const float* __restrict__ bias0, const float* __restrict__ bias1,
    const float* __restrict__ bias2,
    const float* __restrict__ cost, const float* __restrict__ sint,
    bf16* __restrict__ ob0, bf16* __restrict__ ob1, bf16* __restrict__ ob2)
{
  __shared__ bf16 As[128 * 72];
  __shared__ bf16 Bs[128 * 72];
  const int tid = threadIdx.x, lane = tid & 63, wid = tid >> 6;
  const int l15 = lane & 15, lg = lane >> 4;
  const int m0 = blockIdx.x * 128, n0 = blockIdx.y * 128;
  const int wr = (wid >> 1) * 64, wc = (wid & 1) * 64;
  const int srow = tid >> 3, scol = (tid & 7) * 8;

  f4 acc[4][4];
  #pragma unroll
  for (int i = 0; i < 4; i++)
    #pragma unroll
    for (int j = 0; j < 4; j++) acc[i][j] = (f4){0.f, 0.f, 0.f, 0.f};

  bf8v pa[4], pb[4];
  #pragma unroll
  for (int i = 0; i < 4; i++) {
    pa[i] = *(const bf8v*)&A[(size_t)(m0 + srow + i * 32) * 256 + scol];
    pb[i] = *(const bf8v*)&W[(size_t)(n0 + srow + i * 32) * 256 + scol];
  }
  #pragma unroll
  for (int i = 0; i < 4; i++) {
    *(bf8v*)&As[(srow + i * 32) * 72 + scol] = pa[i];
    *(bf8v*)&Bs[(srow + i * 32) * 72 + scol] = pb[i];
  }
  __syncthreads();

  for (int ks = 0; ks < 4; ks++) {
    if (ks < 3) {
      const int kn = (ks + 1) * 64;
      #pragma unroll
      for (int i = 0; i < 4; i++) {
        pa[i] = *(const bf8v*)&A[(size_t)(m0 + srow + i * 32) * 256 + kn + scol];
        pb[i] = *(const bf8v*)&W[(size_t)(n0 + srow + i * 32) * 256 + kn + scol];
      }
    }
    #pragma unroll
    for (int kk = 0; kk < 64; kk += 32) {
      bf8v af[4], bw[4];
      #pragma unroll
      for (int mi = 0; mi < 4; mi++)
        af[mi] = *(const bf8v*)&As[(wr + mi * 16 + l15) * 72 + kk + lg * 8];
      #pragma unroll
      for (int ni = 0; ni < 4; ni++)
        bw[ni] = *(const bf8v*)&Bs[(wc + ni * 16 + l15) * 72 + kk + lg * 8];
      #pragma unroll
      for (int mi = 0; mi < 4; mi++)
        #pragma unroll
        for (int ni = 0; ni < 4; ni++)
          acc[mi][ni] = MFMA(af[mi], bw[ni], acc[mi][ni]);
    }
    __syncthreads();
    if (ks < 3) {
      #pragma unroll
      for (int i = 0; i < 4; i++) {
        *(bf8v*)&As[(srow + i * 32) * 72 + scol] = pa[i];
        *(bf8v*)&Bs[(srow + i * 32) * 72 + scol] = pb[i];
      }
      __syncthreads();
    }
  }

  #pragma unroll
  for (int mi = 0; mi < 4; mi++) {
    #pragma unroll
    for (int ni = 0; ni < 4; ni++) {
      const int nbase = n0 + wc + ni * 16;
      const int n = nbase + l15;
      #pragma unroll
      for (int r = 0; r < 4; r++) {
        const int m = m0 + wr + mi * 16 + lg * 4 + r;
        float v = acc[mi][ni][r];
        if (nbase < 288) {                      // q or k region: rope
          float vb = v + (nbase < 256 ? bias0[n] : bias1[n - 256]);
          int s, hd;
          if (nbase < 256) { const int flat = ((m & 511) << 8) + n; s = (flat >> 5) & 511; hd = n & 31; }
          else             { s = m & 511; hd = n - 256; }
          const float c = cost[s * 32 + hd], sn = sint[s * 32 + hd];
          const float other = __shfl_xor(vb, 1);
          const float res = (n & 1) ? (other * sn + vb * c) : (vb * c - other * sn);
          if (nbase < 256) ob0[(size_t)m * 256 + n] = __float2bfloat16(res);
          else             ob1[(size_t)m * 32 + hd] = __float2bfloat16(res);
        } else if (n < 544) {
          ob2[(size_t)m * 256 + (n - 288)] = __float2bfloat16(v + bias2[n - 288]);
        }
      }
    }
  }
}

// ---------------- fused FFN gate+up GEMM: silu(x2 Wg^T + bg) * (x2 Wu^T + bu) -> g_bf ----
__global__ __launch_bounds__(256) void k_ffn(
    const bf16* __restrict__ A, const bf16* __restrict__ Wg,
    const bf16* __restrict__ Wu,
    const float* __restrict__ bg, const float* __restrict__ bu,
    bf16* __restrict__ out)      // [8192][704]
{
  __shared__ bf16 As[128 * 72];
  __shared__ bf16 Gs[128 * 72];
  __shared__ bf16 Us[128 * 72];
  const int tid = threadIdx.x, lane = tid & 63, wid = tid >> 6;
  const int l15 = lane & 15, lg = lane >> 4;
  const int m0 = blockIdx.x * 128, n0 = blockIdx.y * 128;
  const int wr = (wid >> 1) * 64, wc = (wid & 1) * 64;
  const int srow = tid >> 3, scol = (tid & 7) * 8;

  f4 accg[4][4], accu[4][4];
  #pragma unroll
  for (int i = 0; i < 4; i++)
    #pragma unroll
    for (int j = 0; j < 4; j++) {
      accg[i][j] = (f4){0.f, 0.f, 0.f, 0.f};
      accu[i][j] = (f4){0.f, 0.f, 0.f, 0.f};
    }

  bf8v pa[4], pg[4], pu[4];
  #pragma unroll
  for (int i = 0; i < 4; i++) {
    pa[i] = *(const bf8v*)&A[(size_t)(m0 + srow + i * 32) * 256 + scol];
    pg[i] = *(const bf8v*)&Wg[(size_t)(n0 + srow + i * 32) * 256 + scol];
    pu[i] = *(const bf8v*)&Wu[(size_t)(n0 + srow + i * 32) * 256 + scol];
  }
  #pragma unroll
  for (int i = 0; i < 4; i++) {
    *(bf8v*)&As[(srow + i * 32) * 72 + scol] = pa[i];
    *(bf8v*)&Gs[(srow + i * 32) * 72 + scol] = pg[i];
    *(bf8v*)&Us[(srow + i * 32) * 72 + scol] = pu[i];
  }
  __syncthreads();

  for (int ks = 0; ks < 4; ks++) {
    if (ks < 3) {
      const int kn = (ks + 1) * 64;
      #pragma unroll
      for (int i = 0; i < 4; i++) {
        pa[i] = *(const bf8v*)&A[(size_t)(m0 + srow + i * 32) * 256 + kn + scol];
        pg[i] = *(const bf8v*)&Wg[(size_t)(n0 + srow + i * 32) * 256 + kn + scol];
        pu[i] = *(const bf8v*)&Wu[(size_t)(n0 + srow + i * 32) * 256 + kn + scol];
      }
    }
    #pragma unroll
    for (int kk = 0; kk < 64; kk += 32) {
      bf8v af[4], bgf[4], buf[4];
      #pragma unroll
      for (int mi = 0; mi < 4; mi++)
        af[mi] = *(const bf8v*)&As[(wr + mi * 16 + l15) * 72 + kk + lg * 8];
      #pragma unroll
      for (int ni = 0; ni < 4; ni++) {
        bgf[ni] = *(const bf8v*)&Gs[(wc + ni * 16 + l15) * 72 + kk + lg * 8];
        buf[ni] = *(const bf8v*)&Us[(wc + ni * 16 + l15) * 72 + kk + lg * 8];
      }
      #pragma unroll
      for (int mi = 0; mi < 4; mi++)
        #pragma unroll
        for (int ni = 0; ni < 4; ni++) {
          accg[mi][ni] = MFMA(af[mi], bgf[ni], accg[mi][ni]);
          accu[mi][ni] = MFMA(af[mi], buf[ni], accu[mi][ni]);
        }
    }
    __syncthreads();
    if (ks < 3) {
      #pragma unroll
      for (int i = 0; i < 4; i++) {
        *(bf8v*)&As[(srow + i * 32) * 72 + scol] = pa[i];
        *(bf8v*)&Gs[(srow + i * 32) * 72 + scol] = pg[i];
        *(bf8v*)&Us[(srow + i * 32) * 72 + scol] = pu[i];
      }
      __syncthreads();
    }
  }

  #pragma unroll
  for (int ni = 0; ni < 4; ni++) {
    const int n = n0 + wc + ni * 16 + l15;
    const float bgv = (n < Ff) ? bg[n] : 0.f;
    const float buv = (n < Ff) ? bu[n] : 0.f;
    #pragma unroll
    for (int mi = 0; mi < 4; mi++) {
      #pragma unroll
      for (int r = 0; r < 4; r++) {
        const int m = m0 + wr + mi * 16 + lg * 4 + r;
        if (n < FKp) {
          float res = 0.f;
          if (n < Ff) {
            const float gv = accg[mi][ni][r] + bgv;
            const float uv = accu[mi][ni][r] + buv;
            res = gv / (1.f + __expf(-gv)) * uv;
          }
          out[(size_t)m * FKp + n] = __float2bfloat16(res);
        }
      }
    }
  }
}

// ---------------- down GEMM: out = g_bf Wd^T + b_down + x2, BM=128 BN=64 K=704 ----
__global__ __launch_bounds__(256) void k_down(
    const bf16* __restrict__ A, const bf16* __restrict__ W,
    const float* __restrict__ bias, const float* __restrict__ resid,
    float* __restrict__ out)
{
  __shared__ bf16 As[128 * 72];
  __shared__ bf16 Bs[64 * 72];
  const int tid = threadIdx.x, lane = tid & 63, wid = tid >> 6;
  const int l15 = lane & 15, lg = lane >> 4;
  const int m0 = blockIdx.x * 128, n0 = blockIdx.y * 64;
  const int wr = (wid >> 1) * 64, wc = (wid & 1) * 32;
  const int srow = tid >> 3, scol = (tid & 7) * 8;

  f4 acc[4][2];
  #pragma unroll
  for (int i = 0; i < 4; i++) {
    acc[i][0] = (f4){0.f, 0.f, 0.f, 0.f};
    acc[i][1] = (f4){0.f, 0.f, 0.f, 0.f};
  }

  bf8v pa[4], pb[2];
  #pragma unroll
  for (int i = 0; i < 4; i++)
    pa[i] = *(const bf8v*)&A[(size_t)(m0 + srow + i * 32) * FKp + scol];
  #pragma unroll
  for (int i = 0; i < 2; i++)
    pb[i] = *(const bf8v*)&W[(size_t)(n0 + srow + i * 32) * FKp + scol];
  #pragma unroll
  for (int i = 0; i < 4; i++) *(bf8v*)&As[(srow + i * 32) * 72 + scol] = pa[i];
  #pragma unroll
  for (int i = 0; i < 2; i++) *(bf8v*)&Bs[(srow + i * 32) * 72 + scol] = pb[i];
  __syncthreads();

  for (int ks = 0; ks < 11; ks++) {
    if (ks < 10) {
      const int kn = (ks + 1) * 64;
      #pragma unroll
      for (int i = 0; i < 4; i++)
        pa[i] = *(const bf8v*)&A[(size_t)(m0 + srow + i * 32) * FKp + kn + scol];
      #pragma unroll
      for (int i = 0; i < 2; i++)
        pb[i] = *(const bf8v*)&W[(size_t)(n0 + srow + i * 32) * FKp + kn + scol];
    }
    #pragma unroll
    for (int kk = 0; kk < 64; kk += 32) {
      bf8v af[4], bw[2];
      #pragma unroll
      for (int mi = 0; mi < 4; mi++)
        af[mi] = *(const bf8v*)&As[(wr + mi * 16 + l15) * 72 + kk + lg * 8];
      #pragma unroll
      for (int ni = 0; ni < 2; ni++)
        bw[ni] = *(const bf8v*)&Bs[(wc + ni * 16 + l15) * 72 + kk + lg * 8];
      #pragma unroll
      for (int mi = 0; mi < 4; mi++)
        #pragma unroll
        for (int ni = 0; ni < 2; ni++)
          acc[mi][ni] = MFMA(af[mi], bw[ni], acc[mi][ni]);
    }
    __syncthreads();
    if (ks < 10) {
      #pragma unroll
      for (int i = 0; i < 4; i++) *(bf8v*)&As[(srow + i * 32) * 72 + scol] = pa[i];
      #pragma unroll
      for (int i = 0; i < 2; i++) *(bf8v*)&Bs[(srow + i * 32) * 72 + scol] = pb[i];
      __syncthreads();
    }
  }

  #pragma unroll
  for (int ni = 0; ni < 2; ni++) {
    const int n = n0 + wc + ni * 16 + l15;
    const float bv = bias[n];
    #pragma unroll
    for (int mi = 0; mi < 4; mi++) {
      #pragma unroll
      for (int r = 0; r < 4; r++) {
        const int m = m0 + wr + mi * 16 + lg * 4 + r;
        out[(size_t)m * 256 + n] = acc[mi][ni][r] + bv + resid[(size_t)m * 256 + n];
      }
    }
  }
}

// ---------------- v (B,H,S,HD) bf16 -> vt (B,H,HD,S) bf16 ----------------
__global__ __launch_bounds__(256) void k_vtrans(
    const bf16* __restrict__ v, bf16* __restrict__ vt)
{
  const int bh = blockIdx.y;
  const int s0 = blockIdx.x * 64;
  const int hd = threadIdx.x & 31, sc = threadIdx.x >> 5;   // sc 0..7
  const int s = s0 + sc * 8;
  bf16 tmp[8];
  #pragma unroll
  for (int j = 0; j < 8; j++)
    tmp[j] = v[((size_t)bh * Ss + s + j) * HDd + hd];
  *(bf8v*)&vt[(size_t)bh * (Ss * HDd) + (size_t)hd * Ss + s] = *(const bf8v*)tmp;
}

// ---------------- MFMA flash attention ----------------
__global__ __launch_bounds__(256) void k_attn_mfma(
    const bf16* __restrict__ q, const bf16* __restrict__ k,
    const bf16* __restrict__ vt, float* __restrict__ o)
{
  __shared__ bf16 Ks[64 * 40];       // [t][40 pad]
  __shared__ bf16 Vs[32 * 72];       // [hd][72 pad]  (V transposed)
  __shared__ bf16 Ps[4][16 * 72];    // per wave [q][72 pad]
  const int tid = threadIdx.x, lane = tid & 63, wid = tid >> 6;
  const int l15 = lane & 15, lg = lane >> 4;
  const int qt = blockIdx.x, hh = blockIdx.y, bb = blockIdx.z;
  const int bh = bb * Hh + hh;
  const int qbase = qt * 64 + wid * 16;
  const float scale = 0.17677669529663687f;

  const bf8v qf = *(const bf8v*)&q[((size_t)bh * Ss + qbase + l15) * HDd + lg * 8];

  f4 oacc[2];
  oacc[0] = (f4){0.f, 0.f, 0.f, 0.f};
  oacc[1] = (f4){0.f, 0.f, 0.f, 0.f};
  float mr[4] = {-3.0e38f, -3.0e38f, -3.0e38f, -3.0e38f};
  float lr[4] = {0.f, 0.f, 0.f, 0.f};

  for (int t0 = 0; t0 <= qt * 64; t0 += 64) {
    __syncthreads();
    {
      const int tr = tid >> 2, tc = (tid & 3) * 8;
      *(bf8v*)&Ks[tr * 40 + tc] =
          *(const bf8v*)&k[((size_t)bb * Ss + t0 + tr) * HDd + tc];
      const int hd = tid >> 3, c8 = (tid & 7) * 8;
      *(bf8v*)&Vs[hd * 72 + c8] =
          *(const bf8v*)&vt[(size_t)bh * (Ss * HDd) + (size_t)hd * Ss + t0 + c8];
    }
    __syncthreads();

    f4 sf[4];
    #pragma unroll
    for (int tf = 0; tf < 4; tf++) {
      const bf8v kf = *(const bf8v*)&Ks[(tf * 16 + l15) * 40 + lg * 8];
      sf[tf] = MFMA(qf, kf, (f4){0.f, 0.f, 0.f, 0.f});
    }

    const bool diag = (t0 == qt * 64);
    float pm[4] = {-3.0e38f, -3.0e38f, -3.0e38f, -3.0e38f};
    #pragma unroll
    for (int tf = 0; tf < 4; tf++)
      #pragma unroll
      for (int r = 0; r < 4; r++) {
        float sv = sf[tf][r] * scale;
        if (diag && (t0 + tf * 16 + l15 > qbase + lg * 4 + r)) sv = -3.0e38f;
        sf[tf][r] = sv;
        pm[r] = fmaxf(pm[r], sv);
      }
    #pragma unroll
    for (int r = 0; r < 4; r++) {
      #pragma unroll
      for (int x = 1; x < 16; x <<= 1) pm[r] = fmaxf(pm[r], __shfl_xor(pm[r], x));
    }
    float corr[4];
    #pragma unroll
    for (int r = 0; r < 4; r++) {
      const float nm = fmaxf(mr[r], pm[r]);
      corr[r] = __expf(mr[r] - nm);
      mr[r] = nm;
    }
    float lsum[4] = {0.f, 0.f, 0.f, 0.f};
    #pragma unroll
    for (int tf = 0; tf < 4; tf++)
      #pragma unroll
      for (int r = 0; r < 4; r++) {
        const float p = __expf(sf[tf][r] - mr[r]);
        sf[tf][r] = p;
        lsum[r] += p;
      }
    #pragma unroll
    for (int tf = 0; tf < 4; tf++)
      #pragma unroll
      for (int r = 0; r < 4; r++)
        Ps[wid][(lg * 4 + r) * 72 + tf * 16 + l15] = __float2bfloat16(sf[tf][r]);
    #pragma unroll
    for (int r = 0; r < 4; r++) {
      #pragma unroll
      for (int x = 1; x < 16; x <<= 1) lsum[r] += __shfl_xor(lsum[r], x);
      lr[r] = lr[r] * corr[r] + lsum[r];
    }
    #pragma unroll
    for (int hf = 0; hf < 2; hf++)
      #pragma unroll
      for (int r = 0; r < 4; r++) oacc[hf][r] *= corr[r];

    #pragma unroll
    for (int kt = 0; kt < 2; kt++) {
      const bf8v pa = *(const bf8v*)&Ps[wid][l15 * 72 + kt * 32 + lg * 8];
      #pragma unroll
      for (int hf = 0; hf < 2; hf++) {
        const bf8v vb = *(const bf8v*)&Vs[(hf * 16 + l15) * 72 + kt * 32 + lg * 8];
        oacc[hf] = MFMA(pa, vb, oacc[hf]);
      }
    }
  }

  #pragma unroll
  for (int hf = 0; hf < 2; hf++)
    #pragma unroll
    for (int r = 0; r < 4; r++)
      o[((size_t)bh * Ss + qbase + lg * 4 + r) * HDd + hf * 16 + l15] =
          oacc[hf][r] / lr[r];
}

extern "C" void kernel_launch(void* const* d_in, const int* in_sizes, int n_in,
                              void* d_out, int out_size, void* d_ws, size_t ws_size,
                              hipStream_t stream)
{
  const float* emb     = (const float*)d_in[0];
  const float* pos_emb = (const float*)d_in[1];
  const float* attn_w  = (const float*)d_in[2];
  const float* wq      = (const float*)d_in[3];
  const float* bq      = (const float*)d_in[4];
  const float* wk      = (const float*)d_in[5];
  const float* bk      = (const float*)d_in[6];
  const float* wv      = (const float*)d_in[7];
  const float* bv      = (const float*)d_in[8];
  const float* cos_t   = (const float*)d_in[9];
  const float* sin_t   = (const float*)d_in[10];
  const float* ffn_w   = (const float*)d_in[11];
  const float* w_gate  = (const float*)d_in[12];
  const float* b_gate  = (const float*)d_in[13];
  const float* w_up    = (const float*)d_in[14];
  const float* b_up    = (const float*)d_in[15];
  const float* w_down  = (const float*)d_in[16];
  const float* b_down  = (const float*)d_in[17];
  const int*   tok     = (const int*)d_in[18];
  float* out = (float*)d_out;

  const size_t NT = (size_t)Bb * Ss;   // 8192
  char* base = (char*)d_ws;
  size_t off = 0;
  auto alloc = [&](size_t bytes) {
    void* r = base + off;
    off = (off + bytes + 255) & ~(size_t)255;
    return r;
  };
  float* h      = (float*)alloc(NT * Dd * 4);
  bf16*  x_bf   = (bf16*)alloc(NT * Dd * 2);
  bf16*  q_bf   = (bf16*)alloc(NT * Dd * 2);
  bf16*  k_bf   = (bf16*)alloc(NT * HDd * 2);
  bf16*  v_bf   = (bf16*)alloc(NT * Dd * 2);
  bf16*  vt_bf  = (bf16*)alloc(NT * Dd * 2);
  float* o_     = (float*)alloc(NT * Dd * 4);
  float* x2     = (float*)alloc(NT * Dd * 4);
  bf16*  x2_bf  = (bf16*)alloc(NT * Dd * 2);
  bf16*  g_bf   = (bf16*)alloc(NT * (size_t)FKp * 2);
  bf16*  wqkv_b = (bf16*)alloc((size_t)640 * 256 * 2);
  bf16*  wgate_b= (bf16*)alloc((size_t)768 * 256 * 2);
  bf16*  wup_b  = (bf16*)alloc((size_t)768 * 256 * 2);
  bf16*  wdown_b= (bf16*)alloc((size_t)256 * FKp * 2);

  k_cvt_qkv<<<dim3(640), 256, 0, stream>>>(wq, wk, wv, wqkv_b);
  k_cvt<<<dim3(768), 256, 0, stream>>>(w_gate, wgate_b, 256, 256, 682, 768);
  k_cvt<<<dim3(768), 256, 0, stream>>>(w_up, wup_b, 256, 256, 682, 768);
  k_cvt<<<dim3(704), 256, 0, stream>>>(w_down, wdown_b, 682, FKp, 256, 256);

  k_embed_norm<<<dim3(NT), 256, 0, stream>>>(emb, pos_emb, tok, attn_w, h, x_bf);

  k_qkv<<<dim3(NT / 128, 5), 256, 0, stream>>>(
      x_bf, wqkv_b, bq, bk, bv, cos_t, sin_t, q_bf, k_bf, v_bf);

  k_vtrans<<<dim3(Ss / 64, Bb * Hh), 256, 0, stream>>>(v_bf, vt_bf);

  k_attn_mfma<<<dim3(Ss / 64, Hh, Bb), 256, 0, stream>>>(q_bf, k_bf, vt_bf, o_);

  k_add_norm<<<dim3(NT), 256, 0, stream>>>(o_, h, ffn_w, x2, x2_bf);

  k_ffn<<<dim3(NT / 128, 6), 256, 0, stream>>>(
      x2_bf, wgate_b, wup_b, b_gate, b_up, g_bf);

  k_down<<<dim3(NT / 128, 4), 256, 0, stream>>>(
      g_bf, wdown_b, b_down, x2, out);
}

// Round 5
// 112.529 us; speedup vs baseline: 3.7636x; 1.0355x over previous
//
#include <hip/hip_runtime.h>
#include <hip/hip_bf16.h>
#include <cstddef>
#include <cstdint>

constexpr int Bb = 16, Ss = 512, Dd = 256, Hh = 8, HDd = 32, Ff = 682;
constexpr int FKp = 704;            // padded K for down GEMM (682 -> 704 = 11*64)
constexpr float EPSf = 1.1920928955078125e-07f;

typedef short bf8v __attribute__((ext_vector_type(8)));
typedef float f4 __attribute__((ext_vector_type(4)));
using bf16 = __hip_bfloat16;

__device__ inline f4 MFMA(bf8v a, bf8v b, f4 c) {
  return __builtin_amdgcn_mfma_f32_16x16x32_bf16(a, b, c, 0, 0, 0);
}

// ---------------- embed + rmsnorm -> h(f32), x_bf(bf16) ----------------
__global__ __launch_bounds__(256) void k_embed_norm(
    const float* __restrict__ emb, const float* __restrict__ pos,
    const int* __restrict__ tok, const float* __restrict__ w,
    float* __restrict__ h, bf16* __restrict__ xb)
{
  const int row = blockIdx.x;
  const int s = row & (Ss - 1);
  const int tid = threadIdx.x;
  const int t = tok[row];
  float v = emb[(size_t)t * Dd + tid] + pos[(size_t)s * Dd + tid];
  float ss = v * v;
  #pragma unroll
  for (int off = 32; off > 0; off >>= 1) ss += __shfl_down(ss, off);
  __shared__ float red[4];
  if ((tid & 63) == 0) red[tid >> 6] = ss;
  __syncthreads();
  const float tot = red[0] + red[1] + red[2] + red[3];
  const float r = rsqrtf(tot * (1.0f / Dd) + EPSf);
  const size_t o = (size_t)row * Dd + tid;
  h[o] = v;
  xb[o] = __float2bfloat16(v * r * w[tid]);
}

// ---------------- residual add + rmsnorm -> x2(f32), x2_bf ----------------
__global__ __launch_bounds__(256) void k_add_norm(
    const float* __restrict__ a, const float* __restrict__ hbuf,
    const float* __restrict__ w, float* __restrict__ x2, bf16* __restrict__ x2b)
{
  const int row = blockIdx.x;
  const int tid = threadIdx.x;
  const size_t off = (size_t)row * Dd + tid;
  const float v = a[off] + hbuf[off];
  float ss = v * v;
  #pragma unroll
  for (int o = 32; o > 0; o >>= 1) ss += __shfl_down(ss, o);
  __shared__ float red[4];
  if ((tid & 63) == 0) red[tid >> 6] = ss;
  __syncthreads();
  const float tot = red[0] + red[1] + red[2] + red[3];
  const float r = rsqrtf(tot * (1.0f / Dd) + EPSf);
  const float xv = v * r * w[tid];
  x2[off] = xv;
  x2b[off] = __float2bfloat16(xv);
}

// ---------------- ALL weight converts in one launch ----------------
// blocks:   0..639   qkv pack [640][256]
//         640..1407  gate     [768][256]
//        1408..2175  up       [768][256]
//        2176..2879  down     [256][704] (K=682 padded)
__global__ __launch_bounds__(256) void k_cvt_all(
    const float* __restrict__ wq, const float* __restrict__ wk,
    const float* __restrict__ wv, const float* __restrict__ wg,
    const float* __restrict__ wu, const float* __restrict__ wd,
    bf16* __restrict__ dqkv, bf16* __restrict__ dgate,
    bf16* __restrict__ dup, bf16* __restrict__ ddown)
{
  const int b = blockIdx.x, tid = threadIdx.x;
  if (b < 640) {
    const int idx = b * 256 + tid;
    const int row = idx >> 8, col = idx & 255;
    float v;
    if (row < 256)      v = wq[(size_t)row * 256 + col];
    else if (row < 288) v = wk[(size_t)(row - 256) * 256 + col];
    else if (row < 544) v = wv[(size_t)(row - 288) * 256 + col];
    else                v = 0.f;
    dqkv[idx] = __float2bfloat16(v);
  } else if (b < 2176) {
    const bool isg = b < 1408;
    const int idx = (b - (isg ? 640 : 1408)) * 256 + tid;
    const int row = idx >> 8, col = idx & 255;
    const float* src = isg ? wg : wu;
    float v = (row < Ff) ? src[(size_t)row * 256 + col] : 0.f;
    (isg ? dgate : dup)[idx] = __float2bfloat16(v);
  } else {
    const int idx = (b - 2176) * 256 + tid;   // over [256][704]
    const int row = idx / FKp, col = idx - row * FKp;
    float v = (col < Ff) ? wd[(size_t)row * Ff + col] : 0.f;
    ddown[idx] = __float2bfloat16(v);
  }
}

// ---------------- qkv GEMM: C[m,n] = sum_k x[m,k]*Wqkv[n,k], K=256, rope epilogue ----
__global__ __launch_bounds__(256) void k_qkv(
    const bf16* __restrict__ A, const bf16* __restrict__ W,
    const float* __restrict__ bias0, const float* __restrict__ bias1,
    const float* __restrict__ bias2,
    const float* __restrict__ cost, const float* __restrict__ sint,
    bf16* __restrict__ ob0, bf16* __restrict__ ob1, bf16* __restrict__ ob2)
{
  __shared__ bf16 As[128 * 72];
  __shared__ bf16 Bs[128 * 72];
  const int tid = threadIdx.x, lane = tid & 63, wid = tid >> 6;
  const int l15 = lane & 15, lg = lane >> 4;
  const int m0 = blockIdx.x * 128, n0 = blockIdx.y * 128;
  const int wr = (wid >> 1) * 64, wc = (wid & 1) * 64;
  const int srow = tid >> 3, scol = (tid & 7) * 8;

  f4 acc[4][4];
  #pragma unroll
  for (int i = 0; i < 4; i++)
    #pragma unroll
    for (int j = 0; j < 4; j++) acc[i][j] = (f4){0.f, 0.f, 0.f, 0.f};

  bf8v pa[4], pb[4];
  #pragma unroll
  for (int i = 0; i < 4; i++) {
    pa[i] = *(const bf8v*)&A[(size_t)(m0 + srow + i * 32) * 256 + scol];
    pb[i] = *(const bf8v*)&W[(size_t)(n0 + srow + i * 32) * 256 + scol];
  }
  #pragma unroll
  for (int i = 0; i < 4; i++) {
    *(bf8v*)&As[(srow + i * 32) * 72 + scol] = pa[i];
    *(bf8v*)&Bs[(srow + i * 32) * 72 + scol] = pb[i];
  }
  __syncthreads();

  for (int ks = 0; ks < 4; ks++) {
    if (ks < 3) {
      const int kn = (ks + 1) * 64;
      #pragma unroll
      for (int i = 0; i < 4; i++) {
        pa[i] = *(const bf8v*)&A[(size_t)(m0 + srow + i * 32) * 256 + kn + scol];
        pb[i] = *(const bf8v*)&W[(size_t)(n0 + srow + i * 32) * 256 + kn + scol];
      }
    }
    #pragma unroll
    for (int kk = 0; kk < 64; kk += 32) {
      bf8v af[4], bw[4];
      #pragma unroll
      for (int mi = 0; mi < 4; mi++)
        af[mi] = *(const bf8v*)&As[(wr + mi * 16 + l15) * 72 + kk + lg * 8];
      #pragma unroll
      for (int ni = 0; ni < 4; ni++)
        bw[ni] = *(const bf8v*)&Bs[(wc + ni * 16 + l15) * 72 + kk + lg * 8];
      #pragma unroll
      for (int mi = 0; mi < 4; mi++)
        #pragma unroll
        for (int ni = 0; ni < 4; ni++)
          acc[mi][ni] = MFMA(af[mi], bw[ni], acc[mi][ni]);
    }
    __syncthreads();
    if (ks < 3) {
      #pragma unroll
      for (int i = 0; i < 4; i++) {
        *(bf8v*)&As[(srow + i * 32) * 72 + scol] = pa[i];
        *(bf8v*)&Bs[(srow + i * 32) * 72 + scol] = pb[i];
      }
      __syncthreads();
    }
  }

  #pragma unroll
  for (int mi = 0; mi < 4; mi++) {
    #pragma unroll
    for (int ni = 0; ni < 4; ni++) {
      const int nbase = n0 + wc + ni * 16;
      const int n = nbase + l15;
      #pragma unroll
      for (int r = 0; r < 4; r++) {
        const int m = m0 + wr + mi * 16 + lg * 4 + r;
        float v = acc[mi][ni][r];
        if (nbase < 288) {                      // q or k region: rope
          float vb = v + (nbase < 256 ? bias0[n] : bias1[n - 256]);
          int s, hd;
          if (nbase < 256) { const int flat = ((m & 511) << 8) + n; s = (flat >> 5) & 511; hd = n & 31; }
          else             { s = m & 511; hd = n - 256; }
          const float c = cost[s * 32 + hd], sn = sint[s * 32 + hd];
          const float other = __shfl_xor(vb, 1);
          const float res = (n & 1) ? (other * sn + vb * c) : (vb * c - other * sn);
          if (nbase < 256) ob0[(size_t)m * 256 + n] = __float2bfloat16(res);
          else             ob1[(size_t)m * 32 + hd] = __float2bfloat16(res);
        } else if (n < 544) {
          ob2[(size_t)m * 256 + (n - 288)] = __float2bfloat16(v + bias2[n - 288]);
        }
      }
    }
  }
}

// ---------------- fused FFN gate+up GEMM: silu(x2 Wg^T + bg) * (x2 Wu^T + bu) -> g_bf ----
__global__ __launch_bounds__(256) void k_ffn(
    const bf16* __restrict__ A, const bf16* __restrict__ Wg,
    const bf16* __restrict__ Wu,
    const float* __restrict__ bg, const float* __restrict__ bu,
    bf16* __restrict__ out)      // [8192][704]
{
  __shared__ bf16 As[128 * 72];
  __shared__ bf16 Gs[128 * 72];
  __shared__ bf16 Us[128 * 72];
  const int tid = threadIdx.x, lane = tid & 63, wid = tid >> 6;
  const int l15 = lane & 15, lg = lane >> 4;
  const int m0 = blockIdx.x * 128, n0 = blockIdx.y * 128;
  const int wr = (wid >> 1) * 64, wc = (wid & 1) * 64;
  const int srow = tid >> 3, scol = (tid & 7) * 8;

  f4 accg[4][4], accu[4][4];
  #pragma unroll
  for (int i = 0; i < 4; i++)
    #pragma unroll
    for (int j = 0; j < 4; j++) {
      accg[i][j] = (f4){0.f, 0.f, 0.f, 0.f};
      accu[i][j] = (f4){0.f, 0.f, 0.f, 0.f};
    }

  bf8v pa[4], pg[4], pu[4];
  #pragma unroll
  for (int i = 0; i < 4; i++) {
    pa[i] = *(const bf8v*)&A[(size_t)(m0 + srow + i * 32) * 256 + scol];
    pg[i] = *(const bf8v*)&Wg[(size_t)(n0 + srow + i * 32) * 256 + scol];
    pu[i] = *(const bf8v*)&Wu[(size_t)(n0 + srow + i * 32) * 256 + scol];
  }
  #pragma unroll
  for (int i = 0; i < 4; i++) {
    *(bf8v*)&As[(srow + i * 32) * 72 + scol] = pa[i];
    *(bf8v*)&Gs[(srow + i * 32) * 72 + scol] = pg[i];
    *(bf8v*)&Us[(srow + i * 32) * 72 + scol] = pu[i];
  }
  __syncthreads();

  for (int ks = 0; ks < 4; ks++) {
    if (ks < 3) {
      const int kn = (ks + 1) * 64;
      #pragma unroll
      for (int i = 0; i < 4; i++) {
        pa[i] = *(const bf8v*)&A[(size_t)(m0 + srow + i * 32) * 256 + kn + scol];
        pg[i] = *(const bf8v*)&Wg[(size_t)(n0 + srow + i * 32) * 256 + kn + scol];
        pu[i] = *(const bf8v*)&Wu[(size_t)(n0 + srow + i * 32) * 256 + kn + scol];
      }
    }
    #pragma unroll
    for (int kk = 0; kk < 64; kk += 32) {
      bf8v af[4], bgf[4], buf[4];
      #pragma unroll
      for (int mi = 0; mi < 4; mi++)
        af[mi] = *(const bf8v*)&As[(wr + mi * 16 + l15) * 72 + kk + lg * 8];
      #pragma unroll
      for (int ni = 0; ni < 4; ni++) {
        bgf[ni] = *(const bf8v*)&Gs[(wc + ni * 16 + l15) * 72 + kk + lg * 8];
        buf[ni] = *(const bf8v*)&Us[(wc + ni * 16 + l15) * 72 + kk + lg * 8];
      }
      #pragma unroll
      for (int mi = 0; mi < 4; mi++)
        #pragma unroll
        for (int ni = 0; ni < 4; ni++) {
          accg[mi][ni] = MFMA(af[mi], bgf[ni], accg[mi][ni]);
          accu[mi][ni] = MFMA(af[mi], buf[ni], accu[mi][ni]);
        }
    }
    __syncthreads();
    if (ks < 3) {
      #pragma unroll
      for (int i = 0; i < 4; i++) {
        *(bf8v*)&As[(srow + i * 32) * 72 + scol] = pa[i];
        *(bf8v*)&Gs[(srow + i * 32) * 72 + scol] = pg[i];
        *(bf8v*)&Us[(srow + i * 32) * 72 + scol] = pu[i];
      }
      __syncthreads();
    }
  }

  #pragma unroll
  for (int ni = 0; ni < 4; ni++) {
    const int n = n0 + wc + ni * 16 + l15;
    const float bgv = (n < Ff) ? bg[n] : 0.f;
    const float buv = (n < Ff) ? bu[n] : 0.f;
    #pragma unroll
    for (int mi = 0; mi < 4; mi++) {
      #pragma unroll
      for (int r = 0; r < 4; r++) {
        const int m = m0 + wr + mi * 16 + lg * 4 + r;
        if (n < FKp) {
          float res = 0.f;
          if (n < Ff) {
            const float gv = accg[mi][ni][r] + bgv;
            const float uv = accu[mi][ni][r] + buv;
            res = gv / (1.f + __expf(-gv)) * uv;
          }
          out[(size_t)m * FKp + n] = __float2bfloat16(res);
        }
      }
    }
  }
}

// ---------------- down GEMM: out = g_bf Wd^T + b_down + x2, BM=128 BN=64 K=704 ----
__global__ __launch_bounds__(256) void k_down(
    const bf16* __restrict__ A, const bf16* __restrict__ W,
    const float* __restrict__ bias, const float* __restrict__ resid,
    float* __restrict__ out)
{
  __shared__ bf16 As[128 * 72];
  __shared__ bf16 Bs[64 * 72];
  const int tid = threadIdx.x, lane = tid & 63, wid = tid >> 6;
  const int l15 = lane & 15, lg = lane >> 4;
  const int m0 = blockIdx.x * 128, n0 = blockIdx.y * 64;
  const int wr = (wid >> 1) * 64, wc = (wid & 1) * 32;
  const int srow = tid >> 3, scol = (tid & 7) * 8;

  f4 acc[4][2];
  #pragma unroll
  for (int i = 0; i < 4; i++) {
    acc[i][0] = (f4){0.f, 0.f, 0.f, 0.f};
    acc[i][1] = (f4){0.f, 0.f, 0.f, 0.f};
  }

  bf8v pa[4], pb[2];
  #pragma unroll
  for (int i = 0; i < 4; i++)
    pa[i] = *(const bf8v*)&A[(size_t)(m0 + srow + i * 32) * FKp + scol];
  #pragma unroll
  for (int i = 0; i < 2; i++)
    pb[i] = *(const bf8v*)&W[(size_t)(n0 + srow + i * 32) * FKp + scol];
  #pragma unroll
  for (int i = 0; i < 4; i++) *(bf8v*)&As[(srow + i * 32) * 72 + scol] = pa[i];
  #pragma unroll
  for (int i = 0; i < 2; i++) *(bf8v*)&Bs[(srow + i * 32) * 72 + scol] = pb[i];
  __syncthreads();

  for (int ks = 0; ks < 11; ks++) {
    if (ks < 10) {
      const int kn = (ks + 1) * 64;
      #pragma unroll
      for (int i = 0; i < 4; i++)
        pa[i] = *(const bf8v*)&A[(size_t)(m0 + srow + i * 32) * FKp + kn + scol];
      #pragma unroll
      for (int i = 0; i < 2; i++)
        pb[i] = *(const bf8v*)&W[(size_t)(n0 + srow + i * 32) * FKp + kn + scol];
    }
    #pragma unroll
    for (int kk = 0; kk < 64; kk += 32) {
      bf8v af[4], bw[2];
      #pragma unroll
      for (int mi = 0; mi < 4; mi++)
        af[mi] = *(const bf8v*)&As[(wr + mi * 16 + l15) * 72 + kk + lg * 8];
      #pragma unroll
      for (int ni = 0; ni < 2; ni++)
        bw[ni] = *(const bf8v*)&Bs[(wc + ni * 16 + l15) * 72 + kk + lg * 8];
      #pragma unroll
      for (int mi = 0; mi < 4; mi++)
        #pragma unroll
        for (int ni = 0; ni < 2; ni++)
          acc[mi][ni] = MFMA(af[mi], bw[ni], acc[mi][ni]);
    }
    __syncthreads();
    if (ks < 10) {
      #pragma unroll
      for (int i = 0; i < 4; i++) *(bf8v*)&As[(srow + i * 32) * 72 + scol] = pa[i];
      #pragma unroll
      for (int i = 0; i < 2; i++) *(bf8v*)&Bs[(srow + i * 32) * 72 + scol] = pb[i];
      __syncthreads();
    }
  }

  #pragma unroll
  for (int ni = 0; ni < 2; ni++) {
    const int n = n0 + wc + ni * 16 + l15;
    const float bv = bias[n];
    #pragma unroll
    for (int mi = 0; mi < 4; mi++) {
      #pragma unroll
      for (int r = 0; r < 4; r++) {
        const int m = m0 + wr + mi * 16 + lg * 4 + r;
        out[(size_t)m * 256 + n] = acc[mi][ni][r] + bv + resid[(size_t)m * 256 + n];
      }
    }
  }
}

// ---------------- v (B,H,S,HD) bf16 -> vt (B,H,HD,S) bf16 ----------------
__global__ __launch_bounds__(256) void k_vtrans(
    const bf16* __restrict__ v, bf16* __restrict__ vt)
{
  const int bh = blockIdx.y;
  const int s0 = blockIdx.x * 64;
  const int hd = threadIdx.x & 31, sc = threadIdx.x >> 5;   // sc 0..7
  const int s = s0 + sc * 8;
  bf16 tmp[8];
  #pragma unroll
  for (int j = 0; j < 8; j++)
    tmp[j] = v[((size_t)bh * Ss + s + j) * HDd + hd];
  *(bf8v*)&vt[(size_t)bh * (Ss * HDd) + (size_t)hd * Ss + s] = *(const bf8v*)tmp;
}

// ---------------- MFMA flash attention, 128-row q-tiles ----------------
// grid (S/128=4, H, B), 256 threads = 4 waves, each wave 32 q-rows (2 frags)
__global__ __launch_bounds__(256) void k_attn_mfma(
    const bf16* __restrict__ q, const bf16* __restrict__ k,
    const bf16* __restrict__ vt, float* __restrict__ o)
{
  __shared__ bf16 Ks[64 * 40];       // [t][40 pad]
  __shared__ bf16 Vs[32 * 72];       // [hd][72 pad]  (V transposed)
  __shared__ bf16 Ps[4][32 * 72];    // per wave [q 32][72 pad]
  const int tid = threadIdx.x, lane = tid & 63, wid = tid >> 6;
  const int l15 = lane & 15, lg = lane >> 4;
  const int qt = blockIdx.x, hh = blockIdx.y, bb = blockIdx.z;
  const int bh = bb * Hh + hh;
  const int qbase = qt * 128 + wid * 32;
  const float scale = 0.17677669529663687f;

  bf8v qf[2];
  #pragma unroll
  for (int qi = 0; qi < 2; qi++)
    qf[qi] = *(const bf8v*)&q[((size_t)bh * Ss + qbase + qi * 16 + l15) * HDd + lg * 8];

  f4 oacc[2][2];
  #pragma unroll
  for (int qi = 0; qi < 2; qi++)
    #pragma unroll
    for (int hf = 0; hf < 2; hf++) oacc[qi][hf] = (f4){0.f, 0.f, 0.f, 0.f};
  float mr[2][4], lr[2][4];
  #pragma unroll
  for (int qi = 0; qi < 2; qi++)
    #pragma unroll
    for (int r = 0; r < 4; r++) { mr[qi][r] = -3.0e38f; lr[qi][r] = 0.f; }

  const int tend = (qt + 1) * 128;
  for (int t0 = 0; t0 < tend; t0 += 64) {
    __syncthreads();
    {
      const int tr = tid >> 2, tc = (tid & 3) * 8;
      *(bf8v*)&Ks[tr * 40 + tc] =
          *(const bf8v*)&k[((size_t)bb * Ss + t0 + tr) * HDd + tc];
      const int hd = tid >> 3, c8 = (tid & 7) * 8;
      *(bf8v*)&Vs[hd * 72 + c8] =
          *(const bf8v*)&vt[(size_t)bh * (Ss * HDd) + (size_t)hd * Ss + t0 + c8];
    }
    __syncthreads();

    if (t0 <= qbase + 31) {        // wave-uniform: skip fully-masked tiles
      f4 sf[2][4];
      __builtin_amdgcn_s_setprio(1);
      #pragma unroll
      for (int tf = 0; tf < 4; tf++) {
        const bf8v kf = *(const bf8v*)&Ks[(tf * 16 + l15) * 40 + lg * 8];
        #pragma unroll
        for (int qi = 0; qi < 2; qi++)
          sf[qi][tf] = MFMA(qf[qi], kf, (f4){0.f, 0.f, 0.f, 0.f});
      }
      __builtin_amdgcn_s_setprio(0);

      float pm[2][4];
      #pragma unroll
      for (int qi = 0; qi < 2; qi++) {
        const bool cross = (t0 + 63 > qbase + qi * 16);
        #pragma unroll
        for (int r = 0; r < 4; r++) pm[qi][r] = -3.0e38f;
        #pragma unroll
        for (int tf = 0; tf < 4; tf++)
          #pragma unroll
          for (int r = 0; r < 4; r++) {
            float sv = sf[qi][tf][r] * scale;
            if (cross && (t0 + tf * 16 + l15 > qbase + qi * 16 + lg * 4 + r))
              sv = -3.0e38f;
            sf[qi][tf][r] = sv;
            pm[qi][r] = fmaxf(pm[qi][r], sv);
          }
      }
      float corr[2][4];
      #pragma unroll
      for (int qi = 0; qi < 2; qi++)
        #pragma unroll
        for (int r = 0; r < 4; r++) {
          #pragma unroll
          for (int x = 1; x < 16; x <<= 1)
            pm[qi][r] = fmaxf(pm[qi][r], __shfl_xor(pm[qi][r], x));
          const float nm = fmaxf(mr[qi][r], pm[qi][r]);
          corr[qi][r] = __expf(mr[qi][r] - nm);
          mr[qi][r] = nm;
        }
      float lsum[2][4];
      #pragma unroll
      for (int qi = 0; qi < 2; qi++)
        #pragma unroll
        for (int r = 0; r < 4; r++) lsum[qi][r] = 0.f;
      #pragma unroll
      for (int qi = 0; qi < 2; qi++)
        #pragma unroll
        for (int tf = 0; tf < 4; tf++)
          #pragma unroll
          for (int r = 0; r < 4; r++) {
            const float p = __expf(sf[qi][tf][r] - mr[qi][r]);
            sf[qi][tf][r] = p;
            lsum[qi][r] += p;
          }
      #pragma unroll
      for (int qi = 0; qi < 2; qi++)
        #pragma unroll
        for (int tf = 0; tf < 4; tf++)
          #pragma unroll
          for (int r = 0; r < 4; r++)
            Ps[wid][(qi * 16 + lg * 4 + r) * 72 + tf * 16 + l15] =
                __float2bfloat16(sf[qi][tf][r]);
      #pragma unroll
      for (int qi = 0; qi < 2; qi++)
        #pragma unroll
        for (int r = 0; r < 4; r++) {
          #pragma unroll
          for (int x = 1; x < 16; x <<= 1)
            lsum[qi][r] += __shfl_xor(lsum[qi][r], x);
          lr[qi][r] = lr[qi][r] * corr[qi][r] + lsum[qi][r];
        }
      #pragma unroll
      for (int qi = 0; qi < 2; qi++)
        #pragma unroll
        for (int hf = 0; hf < 2; hf++)
          #pragma unroll
          for (int r = 0; r < 4; r++) oacc[qi][hf][r] *= corr[qi][r];

      __builtin_amdgcn_s_setprio(1);
      #pragma unroll
      for (int kt = 0; kt < 2; kt++) {
        bf8v vb[2];
        #pragma unroll
        for (int hf = 0; hf < 2; hf++)
          vb[hf] = *(const bf8v*)&Vs[(hf * 16 + l15) * 72 + kt * 32 + lg * 8];
        #pragma unroll
        for (int qi = 0; qi < 2; qi++) {
          const bf8v pv = *(const bf8v*)&Ps[wid][(qi * 16 + l15) * 72 + kt * 32 + lg * 8];
          #pragma unroll
          for (int hf = 0; hf < 2; hf++)
            oacc[qi][hf] = MFMA(pv, vb[hf], oacc[qi][hf]);
        }
      }
      __builtin_amdgcn_s_setprio(0);
    }
  }

  #pragma unroll
  for (int qi = 0; qi < 2; qi++)
    #pragma unroll
    for (int hf = 0; hf < 2; hf++)
      #pragma unroll
      for (int r = 0; r < 4; r++)
        o[((size_t)bh * Ss + qbase + qi * 16 + lg * 4 + r) * HDd + hf * 16 + l15] =
            oacc[qi][hf][r] / lr[qi][r];
}

extern "C" void kernel_launch(void* const* d_in, const int* in_sizes, int n_in,
                              void* d_out, int out_size, void* d_ws, size_t ws_size,
                              hipStream_t stream)
{
  const float* emb     = (const float*)d_in[0];
  const float* pos_emb = (const float*)d_in[1];
  const float* attn_w  = (const float*)d_in[2];
  const float* wq      = (const float*)d_in[3];
  const float* bq      = (const float*)d_in[4];
  const float* wk      = (const float*)d_in[5];
  const float* bk      = (const float*)d_in[6];
  const float* wv      = (const float*)d_in[7];
  const float* bv      = (const float*)d_in[8];
  const float* cos_t   = (const float*)d_in[9];
  const float* sin_t   = (const float*)d_in[10];
  const float* ffn_w   = (const float*)d_in[11];
  const float* w_gate  = (const float*)d_in[12];
  const float* b_gate  = (const float*)d_in[13];
  const float* w_up    = (const float*)d_in[14];
  const float* b_up    = (const float*)d_in[15];
  const float* w_down  = (const float*)d_in[16];
  const float* b_down  = (const float*)d_in[17];
  const int*   tok     = (const int*)d_in[18];
  float* out = (float*)d_out;

  const size_t NT = (size_t)Bb * Ss;   // 8192
  char* base = (char*)d_ws;
  size_t off = 0;
  auto alloc = [&](size_t bytes) {
    void* r = base + off;
    off = (off + bytes + 255) & ~(size_t)255;
    return r;
  };
  float* h      = (float*)alloc(NT * Dd * 4);
  bf16*  x_bf   = (bf16*)alloc(NT * Dd * 2);
  bf16*  q_bf   = (bf16*)alloc(NT * Dd * 2);
  bf16*  k_bf   = (bf16*)alloc(NT * HDd * 2);
  bf16*  v_bf   = (bf16*)alloc(NT * Dd * 2);
  bf16*  vt_bf  = (bf16*)alloc(NT * Dd * 2);
  float* o_     = (float*)alloc(NT * Dd * 4);
  float* x2     = (float*)alloc(NT * Dd * 4);
  bf16*  x2_bf  = (bf16*)alloc(NT * Dd * 2);
  bf16*  g_bf   = (bf16*)alloc(NT * (size_t)FKp * 2);
  bf16*  wqkv_b = (bf16*)alloc((size_t)640 * 256 * 2);
  bf16*  wgate_b= (bf16*)alloc((size_t)768 * 256 * 2);
  bf16*  wup_b  = (bf16*)alloc((size_t)768 * 256 * 2);
  bf16*  wdown_b= (bf16*)alloc((size_t)256 * FKp * 2);

  k_cvt_all<<<dim3(2880), 256, 0, stream>>>(
      wq, wk, wv, w_gate, w_up, w_down, wqkv_b, wgate_b, wup_b, wdown_b);

  k_embed_norm<<<dim3(NT), 256, 0, stream>>>(emb, pos_emb, tok, attn_w, h, x_bf);

  k_qkv<<<dim3(NT / 128, 5), 256, 0, stream>>>(
      x_bf, wqkv_b, bq, bk, bv, cos_t, sin_t, q_bf, k_bf, v_bf);

  k_vtrans<<<dim3(Ss / 64, Bb * Hh), 256, 0, stream>>>(v_bf, vt_bf);

  k_attn_mfma<<<dim3(Ss / 128, Hh, Bb), 256, 0, stream>>>(q_bf, k_bf, vt_bf, o_);

  k_add_norm<<<dim3(NT), 256, 0, stream>>>(o_, h, ffn_w, x2, x2_bf);

  k_ffn<<<dim3(NT / 128, 6), 256, 0, stream>>>(
      x2_bf, wgate_b, wup_b, b_gate, b_up, g_bf);

  k_down<<<dim3(NT / 128, 4), 256, 0, stream>>>(
      g_bf, wdown_b, b_down, x2, out);
}

// Round 7
// 106.966 us; speedup vs baseline: 3.9593x; 1.0520x over previous
//
#include <hip/hip_runtime.h>
#include <hip/hip_bf16.h>
#include <cstddef>
#include <cstdint>

constexpr int Bb = 16, Ss = 512, Dd = 256, Hh = 8, HDd = 32, Ff = 682;
constexpr int FKp = 704;            // padded K for down GEMM (682 -> 704 = 11*64)
constexpr float EPSf = 1.1920928955078125e-07f;

typedef short bf8v __attribute__((ext_vector_type(8)));
typedef float f4 __attribute__((ext_vector_type(4)));
using bf16 = __hip_bfloat16;

__device__ inline f4 MFMA(bf8v a, bf8v b, f4 c) {
  return __builtin_amdgcn_mfma_f32_16x16x32_bf16(a, b, c, 0, 0, 0);
}

// ---------------- embed + rmsnorm -> h(f32), x_bf(bf16) ----------------
__global__ __launch_bounds__(256) void k_embed_norm(
    const float* __restrict__ emb, const float* __restrict__ pos,
    const int* __restrict__ tok, const float* __restrict__ w,
    float* __restrict__ h, bf16* __restrict__ xb)
{
  const int row = blockIdx.x;
  const int s = row & (Ss - 1);
  const int tid = threadIdx.x;
  const int t = tok[row];
  float v = emb[(size_t)t * Dd + tid] + pos[(size_t)s * Dd + tid];
  float ss = v * v;
  #pragma unroll
  for (int off = 32; off > 0; off >>= 1) ss += __shfl_down(ss, off);
  __shared__ float red[4];
  if ((tid & 63) == 0) red[tid >> 6] = ss;
  __syncthreads();
  const float tot = red[0] + red[1] + red[2] + red[3];
  const float r = rsqrtf(tot * (1.0f / Dd) + EPSf);
  const size_t o = (size_t)row * Dd + tid;
  h[o] = v;
  xb[o] = __float2bfloat16(v * r * w[tid]);
}

// ---------------- residual add + rmsnorm -> x2(f32), x2_bf ----------------
__global__ __launch_bounds__(256) void k_add_norm(
    const float* __restrict__ a, const float* __restrict__ hbuf,
    const float* __restrict__ w, float* __restrict__ x2, bf16* __restrict__ x2b)
{
  const int row = blockIdx.x;
  const int tid = threadIdx.x;
  const size_t off = (size_t)row * Dd + tid;
  const float v = a[off] + hbuf[off];
  float ss = v * v;
  #pragma unroll
  for (int o = 32; o > 0; o >>= 1) ss += __shfl_down(ss, o);
  __shared__ float red[4];
  if ((tid & 63) == 0) red[tid >> 6] = ss;
  __syncthreads();
  const float tot = red[0] + red[1] + red[2] + red[3];
  const float r = rsqrtf(tot * (1.0f / Dd) + EPSf);
  const float xv = v * r * w[tid];
  x2[off] = xv;
  x2b[off] = __float2bfloat16(xv);
}

// ---------------- ALL weight converts in one launch ----------------
__global__ __launch_bounds__(256) void k_cvt_all(
    const float* __restrict__ wq, const float* __restrict__ wk,
    const float* __restrict__ wv, const float* __restrict__ wg,
    const float* __restrict__ wu, const float* __restrict__ wd,
    bf16* __restrict__ dqkv, bf16* __restrict__ dgate,
    bf16* __restrict__ dup, bf16* __restrict__ ddown)
{
  const int b = blockIdx.x, tid = threadIdx.x;
  if (b < 640) {
    const int idx = b * 256 + tid;
    const int row = idx >> 8, col = idx & 255;
    float v;
    if (row < 256)      v = wq[(size_t)row * 256 + col];
    else if (row < 288) v = wk[(size_t)(row - 256) * 256 + col];
    else if (row < 544) v = wv[(size_t)(row - 288) * 256 + col];
    else                v = 0.f;
    dqkv[idx] = __float2bfloat16(v);
  } else if (b < 2176) {
    const bool isg = b < 1408;
    const int idx = (b - (isg ? 640 : 1408)) * 256 + tid;
    const int row = idx >> 8, col = idx & 255;
    const float* src = isg ? wg : wu;
    float v = (row < Ff) ? src[(size_t)row * 256 + col] : 0.f;
    (isg ? dgate : dup)[idx] = __float2bfloat16(v);
  } else {
    const int idx = (b - 2176) * 256 + tid;   // over [256][704]
    const int row = idx / FKp, col = idx - row * FKp;
    float v = (col < Ff) ? wd[(size_t)row * Ff + col] : 0.f;
    ddown[idx] = __float2bfloat16(v);
  }
}

// ---------------- qkv GEMM: rope epilogue; v written TRANSPOSED (C-order reshape) ----
__global__ __launch_bounds__(256) void k_qkv(
    const bf16* __restrict__ A, const bf16* __restrict__ W,
    const float* __restrict__ bias0, const float* __restrict__ bias1,
    const float* __restrict__ bias2,
    const float* __restrict__ cost, const float* __restrict__ sint,
    bf16* __restrict__ ob0, bf16* __restrict__ ob1, bf16* __restrict__ vt)
{
  __shared__ bf16 As[128 * 72];
  __shared__ bf16 Bs[128 * 72];
  const int tid = threadIdx.x, lane = tid & 63, wid = tid >> 6;
  const int l15 = lane & 15, lg = lane >> 4;
  const int m0 = blockIdx.x * 128, n0 = blockIdx.y * 128;
  const int wr = (wid >> 1) * 64, wc = (wid & 1) * 64;
  const int srow = tid >> 3, scol = (tid & 7) * 8;

  f4 acc[4][4];
  #pragma unroll
  for (int i = 0; i < 4; i++)
    #pragma unroll
    for (int j = 0; j < 4; j++) acc[i][j] = (f4){0.f, 0.f, 0.f, 0.f};

  bf8v pa[4], pb[4];
  #pragma unroll
  for (int i = 0; i < 4; i++) {
    pa[i] = *(const bf8v*)&A[(size_t)(m0 + srow + i * 32) * 256 + scol];
    pb[i] = *(const bf8v*)&W[(size_t)(n0 + srow + i * 32) * 256 + scol];
  }
  #pragma unroll
  for (int i = 0; i < 4; i++) {
    *(bf8v*)&As[(srow + i * 32) * 72 + scol] = pa[i];
    *(bf8v*)&Bs[(srow + i * 32) * 72 + scol] = pb[i];
  }
  __syncthreads();

  for (int ks = 0; ks < 4; ks++) {
    if (ks < 3) {
      const int kn = (ks + 1) * 64;
      #pragma unroll
      for (int i = 0; i < 4; i++) {
        pa[i] = *(const bf8v*)&A[(size_t)(m0 + srow + i * 32) * 256 + kn + scol];
        pb[i] = *(const bf8v*)&W[(size_t)(n0 + srow + i * 32) * 256 + kn + scol];
      }
    }
    #pragma unroll
    for (int kk = 0; kk < 64; kk += 32) {
      bf8v af[4], bw[4];
      #pragma unroll
      for (int mi = 0; mi < 4; mi++)
        af[mi] = *(const bf8v*)&As[(wr + mi * 16 + l15) * 72 + kk + lg * 8];
      #pragma unroll
      for (int ni = 0; ni < 4; ni++)
        bw[ni] = *(const bf8v*)&Bs[(wc + ni * 16 + l15) * 72 + kk + lg * 8];
      #pragma unroll
      for (int mi = 0; mi < 4; mi++)
        #pragma unroll
        for (int ni = 0; ni < 4; ni++)
          acc[mi][ni] = MFMA(af[mi], bw[ni], acc[mi][ni]);
    }
    __syncthreads();
    if (ks < 3) {
      #pragma unroll
      for (int i = 0; i < 4; i++) {
        *(bf8v*)&As[(srow + i * 32) * 72 + scol] = pa[i];
        *(bf8v*)&Bs[(srow + i * 32) * 72 + scol] = pb[i];
      }
      __syncthreads();
    }
  }

  #pragma unroll
  for (int mi = 0; mi < 4; mi++) {
    #pragma unroll
    for (int ni = 0; ni < 4; ni++) {
      const int nbase = n0 + wc + ni * 16;
      const int n = nbase + l15;
      if (nbase < 288) {                      // q or k region: rope
        #pragma unroll
        for (int r = 0; r < 4; r++) {
          const int m = m0 + wr + mi * 16 + lg * 4 + r;
          float vb2 = acc[mi][ni][r] + (nbase < 256 ? bias0[n] : bias1[n - 256]);
          int s, hd;
          if (nbase < 256) { const int flat = ((m & 511) << 8) + n; s = (flat >> 5) & 511; hd = n & 31; }
          else             { s = m & 511; hd = n - 256; }
          const float c = cost[s * 32 + hd], sn = sint[s * 32 + hd];
          const float other = __shfl_xor(vb2, 1);
          const float res = (n & 1) ? (other * sn + vb2 * c) : (vb2 * c - other * sn);
          if (nbase < 256) ob0[(size_t)m * 256 + n] = __float2bfloat16(res);
          else             ob1[(size_t)m * 32 + hd] = __float2bfloat16(res);
        }
      } else if (nbase < 544) {               // v region: transpose via C-order reshape
        const int rel = n - 288;              // feature col in vlin, 0..255
        const int hd = rel & 31, rq = rel >> 5;
        const int mb = m0 + wr + mi * 16 + lg * 4;   // base row, mult of 4
        const int b = mb >> 9;
        const float bv = bias2[rel];
        #pragma unroll
        for (int r = 0; r < 4; r++) {
          const int s = (mb + r) & 511;
          // v4[b][h][s4][hd] = vlin[b][s][rel], F = s*256+rel:
          //   h = s>>6, s4 = (s&63)*8 + rq, hd = rel&31
          const int hh2 = s >> 6;
          const int s4 = ((s & 63) << 3) + rq;
          vt[((size_t)(b * Hh + hh2) * HDd + hd) * Ss + s4] =
              __float2bfloat16(acc[mi][ni][r] + bv);
        }
      }
    }
  }
}

// ---------------- fused FFN gate+up GEMM: silu(x2 Wg^T + bg) * (x2 Wu^T + bu) -> g_bf ----
__global__ __launch_bounds__(256) void k_ffn(
    const bf16* __restrict__ A, const bf16* __restrict__ Wg,
    const bf16* __restrict__ Wu,
    const float* __restrict__ bg, const float* __restrict__ bu,
    bf16* __restrict__ out)      // [8192][704]
{
  __shared__ bf16 As[128 * 72];
  __shared__ bf16 Gs[128 * 72];
  __shared__ bf16 Us[128 * 72];
  const int tid = threadIdx.x, lane = tid & 63, wid = tid >> 6;
  const int l15 = lane & 15, lg = lane >> 4;
  const int m0 = blockIdx.x * 128, n0 = blockIdx.y * 128;
  const int wr = (wid >> 1) * 64, wc = (wid & 1) * 64;
  const int srow = tid >> 3, scol = (tid & 7) * 8;

  f4 accg[4][4], accu[4][4];
  #pragma unroll
  for (int i = 0; i < 4; i++)
    #pragma unroll
    for (int j = 0; j < 4; j++) {
      accg[i][j] = (f4){0.f, 0.f, 0.f, 0.f};
      accu[i][j] = (f4){0.f, 0.f, 0.f, 0.f};
    }

  bf8v pa[4], pg[4], pu[4];
  #pragma unroll
  for (int i = 0; i < 4; i++) {
    pa[i] = *(const bf8v*)&A[(size_t)(m0 + srow + i * 32) * 256 + scol];
    pg[i] = *(const bf8v*)&Wg[(size_t)(n0 + srow + i * 32) * 256 + scol];
    pu[i] = *(const bf8v*)&Wu[(size_t)(n0 + srow + i * 32) * 256 + scol];
  }
  #pragma unroll
  for (int i = 0; i < 4; i++) {
    *(bf8v*)&As[(srow + i * 32) * 72 + scol] = pa[i];
    *(bf8v*)&Gs[(srow + i * 32) * 72 + scol] = pg[i];
    *(bf8v*)&Us[(srow + i * 32) * 72 + scol] = pu[i];
  }
  __syncthreads();

  for (int ks = 0; ks < 4; ks++) {
    if (ks < 3) {
      const int kn = (ks + 1) * 64;
      #pragma unroll
      for (int i = 0; i < 4; i++) {
        pa[i] = *(const bf8v*)&A[(size_t)(m0 + srow + i * 32) * 256 + kn + scol];
        pg[i] = *(const bf8v*)&Wg[(size_t)(n0 + srow + i * 32) * 256 + kn + scol];
        pu[i] = *(const bf8v*)&Wu[(size_t)(n0 + srow + i * 32) * 256 + kn + scol];
      }
    }
    #pragma unroll
    for (int kk = 0; kk < 64; kk += 32) {
      bf8v af[4], bgf[4], buf[4];
      #pragma unroll
      for (int mi = 0; mi < 4; mi++)
        af[mi] = *(const bf8v*)&As[(wr + mi * 16 + l15) * 72 + kk + lg * 8];
      #pragma unroll
      for (int ni = 0; ni < 4; ni++) {
        bgf[ni] = *(const bf8v*)&Gs[(wc + ni * 16 + l15) * 72 + kk + lg * 8];
        buf[ni] = *(const bf8v*)&Us[(wc + ni * 16 + l15) * 72 + kk + lg * 8];
      }
      #pragma unroll
      for (int mi = 0; mi < 4; mi++)
        #pragma unroll
        for (int ni = 0; ni < 4; ni++) {
          accg[mi][ni] = MFMA(af[mi], bgf[ni], accg[mi][ni]);
          accu[mi][ni] = MFMA(af[mi], buf[ni], accu[mi][ni]);
        }
    }
    __syncthreads();
    if (ks < 3) {
      #pragma unroll
      for (int i = 0; i < 4; i++) {
        *(bf8v*)&As[(srow + i * 32) * 72 + scol] = pa[i];
        *(bf8v*)&Gs[(srow + i * 32) * 72 + scol] = pg[i];
        *(bf8v*)&Us[(srow + i * 32) * 72 + scol] = pu[i];
      }
      __syncthreads();
    }
  }

  #pragma unroll
  for (int ni = 0; ni < 4; ni++) {
    const int n = n0 + wc + ni * 16 + l15;
    const float bgv = (n < Ff) ? bg[n] : 0.f;
    const float buv = (n < Ff) ? bu[n] : 0.f;
    #pragma unroll
    for (int mi = 0; mi < 4; mi++) {
      #pragma unroll
      for (int r = 0; r < 4; r++) {
        const int m = m0 + wr + mi * 16 + lg * 4 + r;
        if (n < FKp) {
          float res = 0.f;
          if (n < Ff) {
            const float gv = accg[mi][ni][r] + bgv;
            const float uv = accu[mi][ni][r] + buv;
            res = gv / (1.f + __expf(-gv)) * uv;
          }
          out[(size_t)m * FKp + n] = __float2bfloat16(res);
        }
      }
    }
  }
}

// ---------------- down GEMM: out = g_bf Wd^T + b_down + x2, BM=128 BN=64 K=704 ----
__global__ __launch_bounds__(256) void k_down(
    const bf16* __restrict__ A, const bf16* __restrict__ W,
    const float* __restrict__ bias, const float* __restrict__ resid,
    float* __restrict__ out)
{
  __shared__ bf16 As[128 * 72];
  __shared__ bf16 Bs[64 * 72];
  const int tid = threadIdx.x, lane = tid & 63, wid = tid >> 6;
  const int l15 = lane & 15, lg = lane >> 4;
  const int m0 = blockIdx.x * 128, n0 = blockIdx.y * 64;
  const int wr = (wid >> 1) * 64, wc = (wid & 1) * 32;
  const int srow = tid >> 3, scol = (tid & 7) * 8;

  f4 acc[4][2];
  #pragma unroll
  for (int i = 0; i < 4; i++) {
    acc[i][0] = (f4){0.f, 0.f, 0.f, 0.f};
    acc[i][1] = (f4){0.f, 0.f, 0.f, 0.f};
  }

  bf8v pa[4], pb[2];
  #pragma unroll
  for (int i = 0; i < 4; i++)
    pa[i] = *(const bf8v*)&A[(size_t)(m0 + srow + i * 32) * FKp + scol];
  #pragma unroll
  for (int i = 0; i < 2; i++)
    pb[i] = *(const bf8v*)&W[(size_t)(n0 + srow + i * 32) * FKp + scol];
  #pragma unroll
  for (int i = 0; i < 4; i++) *(bf8v*)&As[(srow + i * 32) * 72 + scol] = pa[i];
  #pragma unroll
  for (int i = 0; i < 2; i++) *(bf8v*)&Bs[(srow + i * 32) * 72 + scol] = pb[i];
  __syncthreads();

  for (int ks = 0; ks < 11; ks++) {
    if (ks < 10) {
      const int kn = (ks + 1) * 64;
      #pragma unroll
      for (int i = 0; i < 4; i++)
        pa[i] = *(const bf8v*)&A[(size_t)(m0 + srow + i * 32) * FKp + kn + scol];
      #pragma unroll
      for (int i = 0; i < 2; i++)
        pb[i] = *(const bf8v*)&W[(size_t)(n0 + srow + i * 32) * FKp + kn + scol];
    }
    #pragma unroll
    for (int kk = 0; kk < 64; kk += 32) {
      bf8v af[4], bw[2];
      #pragma unroll
      for (int mi = 0; mi < 4; mi++)
        af[mi] = *(const bf8v*)&As[(wr + mi * 16 + l15) * 72 + kk + lg * 8];
      #pragma unroll
      for (int ni = 0; ni < 2; ni++)
        bw[ni] = *(const bf8v*)&Bs[(wc + ni * 16 + l15) * 72 + kk + lg * 8];
      #pragma unroll
      for (int mi = 0; mi < 4; mi++)
        #pragma unroll
        for (int ni = 0; ni < 2; ni++)
          acc[mi][ni] = MFMA(af[mi], bw[ni], acc[mi][ni]);
    }
    __syncthreads();
    if (ks < 10) {
      #pragma unroll
      for (int i = 0; i < 4; i++) *(bf8v*)&As[(srow + i * 32) * 72 + scol] = pa[i];
      #pragma unroll
      for (int i = 0; i < 2; i++) *(bf8v*)&Bs[(srow + i * 32) * 72 + scol] = pb[i];
      __syncthreads();
    }
  }

  #pragma unroll
  for (int ni = 0; ni < 2; ni++) {
    const int n = n0 + wc + ni * 16 + l15;
    const float bv = bias[n];
    #pragma unroll
    for (int mi = 0; mi < 4; mi++) {
      #pragma unroll
      for (int r = 0; r < 4; r++) {
        const int m = m0 + wr + mi * 16 + lg * 4 + r;
        out[(size_t)m * 256 + n] = acc[mi][ni][r] + bv + resid[(size_t)m * 256 + n];
      }
    }
  }
}

// ---------------- MFMA flash attention: barrier-free, K/V from L2, balanced ----
// grid (4, H, B), 256 threads = 4 waves. Wave gw = bx*4+wid owns q-rows
// [gw*16, +16) and [496-gw*16, +16) — balanced causal work, ~9 frag-tiles each.
__global__ __launch_bounds__(256) void k_attn_mfma(
    const bf16* __restrict__ q, const bf16* __restrict__ k,
    const bf16* __restrict__ vt, float* __restrict__ o)
{
  __shared__ bf16 Ps[4][2][16 * 72];   // [wave][frag][q16][72] = 18 KB
  const int tid = threadIdx.x, lane = tid & 63, wid = tid >> 6;
  const int l15 = lane & 15, lg = lane >> 4;
  const int hh = blockIdx.y, bb = blockIdx.z;
  const int bh = bb * Hh + hh;
  const int gw = blockIdx.x * 4 + wid;            // 0..15
  const int qrw[2] = {gw * 16, 496 - gw * 16};
  const int lt[2] = {(qrw[0] + 15) >> 6, (qrw[1] + 15) >> 6};
  const float scale = 0.17677669529663687f;

  const bf16* kg = k + (size_t)bb * Ss * HDd;
  const bf16* vg = vt + (size_t)bh * (Ss * HDd);

  bf8v qf[2];
  #pragma unroll
  for (int qi = 0; qi < 2; qi++)
    qf[qi] = *(const bf8v*)&q[((size_t)bh * Ss + qrw[qi] + l15) * HDd + lg * 8];

  f4 oacc[2][2];
  float mr[2][4], lr[2][4];
  #pragma unroll
  for (int qi = 0; qi < 2; qi++) {
    oacc[qi][0] = (f4){0.f, 0.f, 0.f, 0.f};
    oacc[qi][1] = (f4){0.f, 0.f, 0.f, 0.f};
    #pragma unroll
    for (int r = 0; r < 4; r++) { mr[qi][r] = -3.0e38f; lr[qi][r] = 0.f; }
  }

  for (int ti = 0; ti <= lt[1]; ti++) {
    const int t0 = ti * 64;
    const bool act0 = (ti <= lt[0]);

    f4 sf[2][4];
    __builtin_amdgcn_s_setprio(1);
    #pragma unroll
    for (int tf = 0; tf < 4; tf++) {
      const bf8v kf = *(const bf8v*)&kg[(size_t)(t0 + tf * 16 + l15) * HDd + lg * 8];
      sf[1][tf] = MFMA(qf[1], kf, (f4){0.f, 0.f, 0.f, 0.f});
      if (act0) sf[0][tf] = MFMA(qf[0], kf, (f4){0.f, 0.f, 0.f, 0.f});
    }
    __builtin_amdgcn_s_setprio(0);

    // prefetch V fragments (latency hides under softmax)
    bf8v vb[2][2];
    #pragma unroll
    for (int kt = 0; kt < 2; kt++)
      #pragma unroll
      for (int hf = 0; hf < 2; hf++)
        vb[kt][hf] = *(const bf8v*)&vg[(size_t)(hf * 16 + l15) * Ss + t0 + kt * 32 + lg * 8];

    #pragma unroll
    for (int qi = 0; qi < 2; qi++) {
      if (qi == 0 && !act0) continue;
      const int qr = qrw[qi];
      const bool diag = (ti == lt[qi]);
      float pm[4] = {-3.0e38f, -3.0e38f, -3.0e38f, -3.0e38f};
      #pragma unroll
      for (int tf = 0; tf < 4; tf++)
        #pragma unroll
        for (int r = 0; r < 4; r++) {
          float sv = sf[qi][tf][r] * scale;
          if (diag && (t0 + tf * 16 + l15 > qr + lg * 4 + r)) sv = -3.0e38f;
          sf[qi][tf][r] = sv;
          pm[r] = fmaxf(pm[r], sv);
        }
      float corr[4];
      #pragma unroll
      for (int r = 0; r < 4; r++) {
        #pragma unroll
        for (int x = 1; x < 16; x <<= 1) pm[r] = fmaxf(pm[r], __shfl_xor(pm[r], x));
        const float nm = fmaxf(mr[qi][r], pm[r]);
        corr[r] = __expf(mr[qi][r] - nm);
        mr[qi][r] = nm;
      }
      float lsum[4] = {0.f, 0.f, 0.f, 0.f};
      #pragma unroll
      for (int tf = 0; tf < 4; tf++)
        #pragma unroll
        for (int r = 0; r < 4; r++) {
          const float p = __expf(sf[qi][tf][r] - mr[qi][r]);
          sf[qi][tf][r] = p;
          lsum[r] += p;
        }
      #pragma unroll
      for (int tf = 0; tf < 4; tf++)
        #pragma unroll
        for (int r = 0; r < 4; r++)
          Ps[wid][qi][(lg * 4 + r) * 72 + tf * 16 + l15] = __float2bfloat16(sf[qi][tf][r]);
      #pragma unroll
      for (int r = 0; r < 4; r++) {
        #pragma unroll
        for (int x = 1; x < 16; x <<= 1) lsum[r] += __shfl_xor(lsum[r], x);
        lr[qi][r] = lr[qi][r] * corr[r] + lsum[r];
      }
      #pragma unroll
      for (int hf = 0; hf < 2; hf++)
        #pragma unroll
        for (int r = 0; r < 4; r++) oacc[qi][hf][r] *= corr[r];

      __builtin_amdgcn_s_setprio(1);
      #pragma unroll
      for (int kt = 0; kt < 2; kt++) {
        const bf8v pv = *(const bf8v*)&Ps[wid][qi][l15 * 72 + kt * 32 + lg * 8];
        #pragma unroll
        for (int hf = 0; hf < 2; hf++)
          oacc[qi][hf] = MFMA(pv, vb[kt][hf], oacc[qi][hf]);
      }
      __builtin_amdgcn_s_setprio(0);
    }
  }

  #pragma unroll
  for (int qi = 0; qi < 2; qi++)
    #pragma unroll
    for (int hf = 0; hf < 2; hf++)
      #pragma unroll
      for (int r = 0; r < 4; r++)
        o[((size_t)bh * Ss + qrw[qi] + lg * 4 + r) * HDd + hf * 16 + l15] =
            oacc[qi][hf][r] / lr[qi][r];
}

extern "C" void kernel_launch(void* const* d_in, const int* in_sizes, int n_in,
                              void* d_out, int out_size, void* d_ws, size_t ws_size,
                              hipStream_t stream)
{
  const float* emb     = (const float*)d_in[0];
  const float* pos_emb = (const float*)d_in[1];
  const float* attn_w  = (const float*)d_in[2];
  const float* wq      = (const float*)d_in[3];
  const float* bq      = (const float*)d_in[4];
  const float* wk      = (const float*)d_in[5];
  const float* bk      = (const float*)d_in[6];
  const float* wv      = (const float*)d_in[7];
  const float* bv      = (const float*)d_in[8];
  const float* cos_t   = (const float*)d_in[9];
  const float* sin_t   = (const float*)d_in[10];
  const float* ffn_w   = (const float*)d_in[11];
  const float* w_gate  = (const float*)d_in[12];
  const float* b_gate  = (const float*)d_in[13];
  const float* w_up    = (const float*)d_in[14];
  const float* b_up    = (const float*)d_in[15];
  const float* w_down  = (const float*)d_in[16];
  const float* b_down  = (const float*)d_in[17];
  const int*   tok     = (const int*)d_in[18];
  float* out = (float*)d_out;

  const size_t NT = (size_t)Bb * Ss;   // 8192
  char* base = (char*)d_ws;
  size_t off = 0;
  auto alloc = [&](size_t bytes) {
    void* r = base + off;
    off = (off + bytes + 255) & ~(size_t)255;
    return r;
  };
  float* h      = (float*)alloc(NT * Dd * 4);
  bf16*  x_bf   = (bf16*)alloc(NT * Dd * 2);
  bf16*  q_bf   = (bf16*)alloc(NT * Dd * 2);
  bf16*  k_bf   = (bf16*)alloc(NT * HDd * 2);
  bf16*  vt_bf  = (bf16*)alloc(NT * Dd * 2);
  float* o_     = (float*)alloc(NT * Dd * 4);
  float* x2     = (float*)alloc(NT * Dd * 4);
  bf16*  x2_bf  = (bf16*)alloc(NT * Dd * 2);
  bf16*  g_bf   = (bf16*)alloc(NT * (size_t)FKp * 2);
  bf16*  wqkv_b = (bf16*)alloc((size_t)640 * 256 * 2);
  bf16*  wgate_b= (bf16*)alloc((size_t)768 * 256 * 2);
  bf16*  wup_b  = (bf16*)alloc((size_t)768 * 256 * 2);
  bf16*  wdown_b= (bf16*)alloc((size_t)256 * FKp * 2);

  k_cvt_all<<<dim3(2880), 256, 0, stream>>>(
      wq, wk, wv, w_gate, w_up, w_down, wqkv_b, wgate_b, wup_b, wdown_b);

  k_embed_norm<<<dim3(NT), 256, 0, stream>>>(emb, pos_emb, tok, attn_w, h, x_bf);

  k_qkv<<<dim3(NT / 128, 5), 256, 0, stream>>>(
      x_bf, wqkv_b, bq, bk, bv, cos_t, sin_t, q_bf, k_bf, vt_bf);

  k_attn_mfma<<<dim3(4, Hh, Bb), 256, 0, stream>>>(q_bf, k_bf, vt_bf, o_);

  k_add_norm<<<dim3(NT), 256, 0, stream>>>(o_, h, ffn_w, x2, x2_bf);

  k_ffn<<<dim3(NT / 128, 6), 256, 0, stream>>>(
      x2_bf, wgate_b, wup_b, b_gate, b_up, g_bf);

  k_down<<<dim3(NT / 128, 4), 256, 0, stream>>>(
      g_bf, wdown_b, b_down, x2, out);
}

// Round 8
// 94.763 us; speedup vs baseline: 4.4692x; 1.1288x over previous
//
#include <hip/hip_runtime.h>
#include <hip/hip_bf16.h>
#include <cstddef>
#include <cstdint>

constexpr int Bb = 16, Ss = 512, Dd = 256, Hh = 8, HDd = 32, Ff = 682;
constexpr int FKp = 704;            // padded K for down GEMM (682 -> 704 = 11*64)
constexpr float EPSf = 1.1920928955078125e-07f;

typedef short bf8v __attribute__((ext_vector_type(8)));
typedef float f4 __attribute__((ext_vector_type(4)));
using bf16 = __hip_bfloat16;

__device__ inline f4 MFMA(bf8v a, bf8v b, f4 c) {
  return __builtin_amdgcn_mfma_f32_16x16x32_bf16(a, b, c, 0, 0, 0);
}

// ---------------- embed + rmsnorm -> h_bf(bf16), x_bf(bf16) ----------------
__global__ __launch_bounds__(256) void k_embed_norm(
    const float* __restrict__ emb, const float* __restrict__ pos,
    const int* __restrict__ tok, const float* __restrict__ w,
    bf16* __restrict__ hb, bf16* __restrict__ xb)
{
  const int row = blockIdx.x;
  const int s = row & (Ss - 1);
  const int tid = threadIdx.x;
  const int t = tok[row];
  float v = emb[(size_t)t * Dd + tid] + pos[(size_t)s * Dd + tid];
  float ss = v * v;
  #pragma unroll
  for (int off = 32; off > 0; off >>= 1) ss += __shfl_down(ss, off);
  __shared__ float red[4];
  if ((tid & 63) == 0) red[tid >> 6] = ss;
  __syncthreads();
  const float tot = red[0] + red[1] + red[2] + red[3];
  const float r = rsqrtf(tot * (1.0f / Dd) + EPSf);
  const size_t o = (size_t)row * Dd + tid;
  hb[o] = __float2bfloat16(v);
  xb[o] = __float2bfloat16(v * r * w[tid]);
}

// ---------------- residual add + rmsnorm -> x2_bf ----------------
__global__ __launch_bounds__(256) void k_add_norm(
    const bf16* __restrict__ a, const bf16* __restrict__ hb,
    const float* __restrict__ w, bf16* __restrict__ x2b)
{
  const int row = blockIdx.x;
  const int tid = threadIdx.x;
  const size_t off = (size_t)row * Dd + tid;
  const float v = __bfloat162float(a[off]) + __bfloat162float(hb[off]);
  float ss = v * v;
  #pragma unroll
  for (int o = 32; o > 0; o >>= 1) ss += __shfl_down(ss, o);
  __shared__ float red[4];
  if ((tid & 63) == 0) red[tid >> 6] = ss;
  __syncthreads();
  const float tot = red[0] + red[1] + red[2] + red[3];
  const float r = rsqrtf(tot * (1.0f / Dd) + EPSf);
  x2b[off] = __float2bfloat16(v * r * w[tid]);
}

// ---------------- ALL weight converts in one launch ----------------
__global__ __launch_bounds__(256) void k_cvt_all(
    const float* __restrict__ wq, const float* __restrict__ wk,
    const float* __restrict__ wv, const float* __restrict__ wg,
    const float* __restrict__ wu, const float* __restrict__ wd,
    bf16* __restrict__ dqkv, bf16* __restrict__ dgate,
    bf16* __restrict__ dup, bf16* __restrict__ ddown)
{
  const int b = blockIdx.x, tid = threadIdx.x;
  if (b < 640) {
    const int idx = b * 256 + tid;
    const int row = idx >> 8, col = idx & 255;
    float v;
    if (row < 256)      v = wq[(size_t)row * 256 + col];
    else if (row < 288) v = wk[(size_t)(row - 256) * 256 + col];
    else if (row < 544) v = wv[(size_t)(row - 288) * 256 + col];
    else                v = 0.f;
    dqkv[idx] = __float2bfloat16(v);
  } else if (b < 2176) {
    const bool isg = b < 1408;
    const int idx = (b - (isg ? 640 : 1408)) * 256 + tid;
    const int row = idx >> 8, col = idx & 255;
    const float* src = isg ? wg : wu;
    float v = (row < Ff) ? src[(size_t)row * 256 + col] : 0.f;
    (isg ? dgate : dup)[idx] = __float2bfloat16(v);
  } else {
    const int idx = (b - 2176) * 256 + tid;   // over [256][704]
    const int row = idx / FKp, col = idx - row * FKp;
    float v = (col < Ff) ? wd[(size_t)row * Ff + col] : 0.f;
    ddown[idx] = __float2bfloat16(v);
  }
}

// ---------------- qkv GEMM: BM=128 BN=64 K=256, rope epilogue, V transposed ----
__global__ __launch_bounds__(256) void k_qkv(
    const bf16* __restrict__ A, const bf16* __restrict__ W,
    const float* __restrict__ bias0, const float* __restrict__ bias1,
    const float* __restrict__ bias2,
    const float* __restrict__ cost, const float* __restrict__ sint,
    bf16* __restrict__ ob0, bf16* __restrict__ ob1, bf16* __restrict__ vt)
{
  __shared__ bf16 As[128 * 72];
  __shared__ bf16 Bs[64 * 72];
  const int tid = threadIdx.x, lane = tid & 63, wid = tid >> 6;
  const int l15 = lane & 15, lg = lane >> 4;
  const int m0 = blockIdx.x * 128, n0 = blockIdx.y * 64;
  const int wr = (wid >> 1) * 64, wc = (wid & 1) * 32;
  const int srow = tid >> 3, scol = (tid & 7) * 8;

  f4 acc[4][2];
  #pragma unroll
  for (int i = 0; i < 4; i++)
    #pragma unroll
    for (int j = 0; j < 2; j++) acc[i][j] = (f4){0.f, 0.f, 0.f, 0.f};

  bf8v pa[4], pb[2];
  #pragma unroll
  for (int i = 0; i < 4; i++)
    pa[i] = *(const bf8v*)&A[(size_t)(m0 + srow + i * 32) * 256 + scol];
  #pragma unroll
  for (int i = 0; i < 2; i++)
    pb[i] = *(const bf8v*)&W[(size_t)(n0 + srow + i * 32) * 256 + scol];
  #pragma unroll
  for (int i = 0; i < 4; i++) *(bf8v*)&As[(srow + i * 32) * 72 + scol] = pa[i];
  #pragma unroll
  for (int i = 0; i < 2; i++) *(bf8v*)&Bs[(srow + i * 32) * 72 + scol] = pb[i];
  __syncthreads();

  for (int ks = 0; ks < 4; ks++) {
    if (ks < 3) {
      const int kn = (ks + 1) * 64;
      #pragma unroll
      for (int i = 0; i < 4; i++)
        pa[i] = *(const bf8v*)&A[(size_t)(m0 + srow + i * 32) * 256 + kn + scol];
      #pragma unroll
      for (int i = 0; i < 2; i++)
        pb[i] = *(const bf8v*)&W[(size_t)(n0 + srow + i * 32) * 256 + kn + scol];
    }
    #pragma unroll
    for (int kk = 0; kk < 64; kk += 32) {
      bf8v af[4], bw[2];
      #pragma unroll
      for (int mi = 0; mi < 4; mi++)
        af[mi] = *(const bf8v*)&As[(wr + mi * 16 + l15) * 72 + kk + lg * 8];
      #pragma unroll
      for (int ni = 0; ni < 2; ni++)
        bw[ni] = *(const bf8v*)&Bs[(wc + ni * 16 + l15) * 72 + kk + lg * 8];
      #pragma unroll
      for (int mi = 0; mi < 4; mi++)
        #pragma unroll
        for (int ni = 0; ni < 2; ni++)
          acc[mi][ni] = MFMA(af[mi], bw[ni], acc[mi][ni]);
    }
    __syncthreads();
    if (ks < 3) {
      #pragma unroll
      for (int i = 0; i < 4; i++) *(bf8v*)&As[(srow + i * 32) * 72 + scol] = pa[i];
      #pragma unroll
      for (int i = 0; i < 2; i++) *(bf8v*)&Bs[(srow + i * 32) * 72 + scol] = pb[i];
      __syncthreads();
    }
  }

  #pragma unroll
  for (int mi = 0; mi < 4; mi++) {
    #pragma unroll
    for (int ni = 0; ni < 2; ni++) {
      const int nbase = n0 + wc + ni * 16;
      const int n = nbase + l15;
      if (nbase < 288) {                      // q or k region: rope
        #pragma unroll
        for (int r = 0; r < 4; r++) {
          const int m = m0 + wr + mi * 16 + lg * 4 + r;
          float vb2 = acc[mi][ni][r] + (nbase < 256 ? bias0[n] : bias1[n - 256]);
          int s, hd;
          if (nbase < 256) { const int flat = ((m & 511) << 8) + n; s = (flat >> 5) & 511; hd = n & 31; }
          else             { s = m & 511; hd = n - 256; }
          const float c = cost[s * 32 + hd], sn = sint[s * 32 + hd];
          const float other = __shfl_xor(vb2, 1);
          const float res = (n & 1) ? (other * sn + vb2 * c) : (vb2 * c - other * sn);
          if (nbase < 256) ob0[(size_t)m * 256 + n] = __float2bfloat16(res);
          else             ob1[(size_t)m * 32 + hd] = __float2bfloat16(res);
        }
      } else if (nbase < 544) {               // v region: transpose via C-order reshape
        const int rel = n - 288;              // feature col in vlin, 0..255
        const int hd = rel & 31, rq = rel >> 5;
        const int mb = m0 + wr + mi * 16 + lg * 4;   // base row, mult of 4
        const int b = mb >> 9;
        const float bv = bias2[rel];
        #pragma unroll
        for (int r = 0; r < 4; r++) {
          const int s = (mb + r) & 511;
          // v4[b][h][s4][hd] = vlin[b][s][rel]:  h = s>>6, s4 = (s&63)*8 + rq
          const int hh2 = s >> 6;
          const int s4 = ((s & 63) << 3) + rq;
          vt[((size_t)(b * Hh + hh2) * HDd + hd) * Ss + s4] =
              __float2bfloat16(acc[mi][ni][r] + bv);
        }
      }
    }
  }
}

// ---------------- fused FFN gate+up: BM=128 BN=64 -> g_bf [8192][704] ----
__global__ __launch_bounds__(256) void k_ffn(
    const bf16* __restrict__ A, const bf16* __restrict__ Wg,
    const bf16* __restrict__ Wu,
    const float* __restrict__ bg, const float* __restrict__ bu,
    bf16* __restrict__ out)
{
  __shared__ bf16 As[128 * 72];
  __shared__ bf16 Gs[64 * 72];
  __shared__ bf16 Us[64 * 72];
  const int tid = threadIdx.x, lane = tid & 63, wid = tid >> 6;
  const int l15 = lane & 15, lg = lane >> 4;
  const int m0 = blockIdx.x * 128, n0 = blockIdx.y * 64;
  const int wr = (wid >> 1) * 64, wc = (wid & 1) * 32;
  const int srow = tid >> 3, scol = (tid & 7) * 8;

  f4 accg[4][2], accu[4][2];
  #pragma unroll
  for (int i = 0; i < 4; i++)
    #pragma unroll
    for (int j = 0; j < 2; j++) {
      accg[i][j] = (f4){0.f, 0.f, 0.f, 0.f};
      accu[i][j] = (f4){0.f, 0.f, 0.f, 0.f};
    }

  bf8v pa[4], pg[2], pu[2];
  #pragma unroll
  for (int i = 0; i < 4; i++)
    pa[i] = *(const bf8v*)&A[(size_t)(m0 + srow + i * 32) * 256 + scol];
  #pragma unroll
  for (int i = 0; i < 2; i++) {
    pg[i] = *(const bf8v*)&Wg[(size_t)(n0 + srow + i * 32) * 256 + scol];
    pu[i] = *(const bf8v*)&Wu[(size_t)(n0 + srow + i * 32) * 256 + scol];
  }
  #pragma unroll
  for (int i = 0; i < 4; i++) *(bf8v*)&As[(srow + i * 32) * 72 + scol] = pa[i];
  #pragma unroll
  for (int i = 0; i < 2; i++) {
    *(bf8v*)&Gs[(srow + i * 32) * 72 + scol] = pg[i];
    *(bf8v*)&Us[(srow + i * 32) * 72 + scol] = pu[i];
  }
  __syncthreads();

  for (int ks = 0; ks < 4; ks++) {
    if (ks < 3) {
      const int kn = (ks + 1) * 64;
      #pragma unroll
      for (int i = 0; i < 4; i++)
        pa[i] = *(const bf8v*)&A[(size_t)(m0 + srow + i * 32) * 256 + kn + scol];
      #pragma unroll
      for (int i = 0; i < 2; i++) {
        pg[i] = *(const bf8v*)&Wg[(size_t)(n0 + srow + i * 32) * 256 + kn + scol];
        pu[i] = *(const bf8v*)&Wu[(size_t)(n0 + srow + i * 32) * 256 + kn + scol];
      }
    }
    #pragma unroll
    for (int kk = 0; kk < 64; kk += 32) {
      bf8v af[4], bgf[2], buf[2];
      #pragma unroll
      for (int mi = 0; mi < 4; mi++)
        af[mi] = *(const bf8v*)&As[(wr + mi * 16 + l15) * 72 + kk + lg * 8];
      #pragma unroll
      for (int ni = 0; ni < 2; ni++) {
        bgf[ni] = *(const bf8v*)&Gs[(wc + ni * 16 + l15) * 72 + kk + lg * 8];
        buf[ni] = *(const bf8v*)&Us[(wc + ni * 16 + l15) * 72 + kk + lg * 8];
      }
      #pragma unroll
      for (int mi = 0; mi < 4; mi++)
        #pragma unroll
        for (int ni = 0; ni < 2; ni++) {
          accg[mi][ni] = MFMA(af[mi], bgf[ni], accg[mi][ni]);
          accu[mi][ni] = MFMA(af[mi], buf[ni], accu[mi][ni]);
        }
    }
    __syncthreads();
    if (ks < 3) {
      #pragma unroll
      for (int i = 0; i < 4; i++) *(bf8v*)&As[(srow + i * 32) * 72 + scol] = pa[i];
      #pragma unroll
      for (int i = 0; i < 2; i++) {
        *(bf8v*)&Gs[(srow + i * 32) * 72 + scol] = pg[i];
        *(bf8v*)&Us[(srow + i * 32) * 72 + scol] = pu[i];
      }
      __syncthreads();
    }
  }

  #pragma unroll
  for (int ni = 0; ni < 2; ni++) {
    const int n = n0 + wc + ni * 16 + l15;
    const float bgv = (n < Ff) ? bg[n] : 0.f;
    const float buv = (n < Ff) ? bu[n] : 0.f;
    #pragma unroll
    for (int mi = 0; mi < 4; mi++) {
      #pragma unroll
      for (int r = 0; r < 4; r++) {
        const int m = m0 + wr + mi * 16 + lg * 4 + r;
        float res = 0.f;
        if (n < Ff) {
          const float gv = accg[mi][ni][r] + bgv;
          const float uv = accu[mi][ni][r] + buv;
          res = gv / (1.f + __expf(-gv)) * uv;
        }
        out[(size_t)m * FKp + n] = __float2bfloat16(res);
      }
    }
  }
}

// ---------------- down GEMM: BM=64 BN=64 K=704, +bias +resid(bf16) -> out f32 ----
__global__ __launch_bounds__(256) void k_down(
    const bf16* __restrict__ A, const bf16* __restrict__ W,
    const float* __restrict__ bias, const bf16* __restrict__ resid,
    float* __restrict__ out)
{
  __shared__ bf16 As[64 * 72];
  __shared__ bf16 Bs[64 * 72];
  const int tid = threadIdx.x, lane = tid & 63, wid = tid >> 6;
  const int l15 = lane & 15, lg = lane >> 4;
  const int m0 = blockIdx.x * 64, n0 = blockIdx.y * 64;
  const int wr = (wid >> 1) * 32, wc = (wid & 1) * 32;
  const int srow = tid >> 3, scol = (tid & 7) * 8;

  f4 acc[2][2];
  #pragma unroll
  for (int i = 0; i < 2; i++)
    #pragma unroll
    for (int j = 0; j < 2; j++) acc[i][j] = (f4){0.f, 0.f, 0.f, 0.f};

  bf8v pa[2], pb[2];
  #pragma unroll
  for (int i = 0; i < 2; i++) {
    pa[i] = *(const bf8v*)&A[(size_t)(m0 + srow + i * 32) * FKp + scol];
    pb[i] = *(const bf8v*)&W[(size_t)(n0 + srow + i * 32) * FKp + scol];
  }
  #pragma unroll
  for (int i = 0; i < 2; i++) {
    *(bf8v*)&As[(srow + i * 32) * 72 + scol] = pa[i];
    *(bf8v*)&Bs[(srow + i * 32) * 72 + scol] = pb[i];
  }
  __syncthreads();

  for (int ks = 0; ks < 11; ks++) {
    if (ks < 10) {
      const int kn = (ks + 1) * 64;
      #pragma unroll
      for (int i = 0; i < 2; i++) {
        pa[i] = *(const bf8v*)&A[(size_t)(m0 + srow + i * 32) * FKp + kn + scol];
        pb[i] = *(const bf8v*)&W[(size_t)(n0 + srow + i * 32) * FKp + kn + scol];
      }
    }
    #pragma unroll
    for (int kk = 0; kk < 64; kk += 32) {
      bf8v af[2], bw[2];
      #pragma unroll
      for (int mi = 0; mi < 2; mi++)
        af[mi] = *(const bf8v*)&As[(wr + mi * 16 + l15) * 72 + kk + lg * 8];
      #pragma unroll
      for (int ni = 0; ni < 2; ni++)
        bw[ni] = *(const bf8v*)&Bs[(wc + ni * 16 + l15) * 72 + kk + lg * 8];
      #pragma unroll
      for (int mi = 0; mi < 2; mi++)
        #pragma unroll
        for (int ni = 0; ni < 2; ni++)
          acc[mi][ni] = MFMA(af[mi], bw[ni], acc[mi][ni]);
    }
    __syncthreads();
    if (ks < 10) {
      #pragma unroll
      for (int i = 0; i < 2; i++) {
        *(bf8v*)&As[(srow + i * 32) * 72 + scol] = pa[i];
        *(bf8v*)&Bs[(srow + i * 32) * 72 + scol] = pb[i];
      }
      __syncthreads();
    }
  }

  #pragma unroll
  for (int ni = 0; ni < 2; ni++) {
    const int n = n0 + wc + ni * 16 + l15;
    const float bv = bias[n];
    #pragma unroll
    for (int mi = 0; mi < 2; mi++) {
      #pragma unroll
      for (int r = 0; r < 4; r++) {
        const int m = m0 + wr + mi * 16 + lg * 4 + r;
        out[(size_t)m * 256 + n] = acc[mi][ni][r] + bv +
            __bfloat162float(resid[(size_t)m * 256 + n]);
      }
    }
  }
}

// ---------------- MFMA flash attention: barrier-free, K/V from L2, balanced ----
__global__ __launch_bounds__(256) void k_attn_mfma(
    const bf16* __restrict__ q, const bf16* __restrict__ k,
    const bf16* __restrict__ vt, bf16* __restrict__ o)
{
  __shared__ bf16 Ps[4][2][16 * 72];   // [wave][frag][q16][72] = 18 KB
  const int tid = threadIdx.x, lane = tid & 63, wid = tid >> 6;
  const int l15 = lane & 15, lg = lane >> 4;
  const int hh = blockIdx.y, bb = blockIdx.z;
  const int bh = bb * Hh + hh;
  const int gw = blockIdx.x * 4 + wid;            // 0..15
  const int qrw[2] = {gw * 16, 496 - gw * 16};
  const int lt[2] = {(qrw[0] + 15) >> 6, (qrw[1] + 15) >> 6};
  const float scale = 0.17677669529663687f;

  const bf16* kg = k + (size_t)bb * Ss * HDd;
  const bf16* vg = vt + (size_t)bh * (Ss * HDd);

  bf8v qf[2];
  #pragma unroll
  for (int qi = 0; qi < 2; qi++)
    qf[qi] = *(const bf8v*)&q[((size_t)bh * Ss + qrw[qi] + l15) * HDd + lg * 8];

  f4 oacc[2][2];
  float mr[2][4], lr[2][4];
  #pragma unroll
  for (int qi = 0; qi < 2; qi++) {
    oacc[qi][0] = (f4){0.f, 0.f, 0.f, 0.f};
    oacc[qi][1] = (f4){0.f, 0.f, 0.f, 0.f};
    #pragma unroll
    for (int r = 0; r < 4; r++) { mr[qi][r] = -3.0e38f; lr[qi][r] = 0.f; }
  }

  for (int ti = 0; ti <= lt[1]; ti++) {
    const int t0 = ti * 64;
    const bool act0 = (ti <= lt[0]);

    f4 sf[2][4];
    __builtin_amdgcn_s_setprio(1);
    #pragma unroll
    for (int tf = 0; tf < 4; tf++) {
      const bf8v kf = *(const bf8v*)&kg[(size_t)(t0 + tf * 16 + l15) * HDd + lg * 8];
      sf[1][tf] = MFMA(qf[1], kf, (f4){0.f, 0.f, 0.f, 0.f});
      if (act0) sf[0][tf] = MFMA(qf[0], kf, (f4){0.f, 0.f, 0.f, 0.f});
    }
    __builtin_amdgcn_s_setprio(0);

    // prefetch V fragments (latency hides under softmax)
    bf8v vb[2][2];
    #pragma unroll
    for (int kt = 0; kt < 2; kt++)
      #pragma unroll
      for (int hf = 0; hf < 2; hf++)
        vb[kt][hf] = *(const bf8v*)&vg[(size_t)(hf * 16 + l15) * Ss + t0 + kt * 32 + lg * 8];

    #pragma unroll
    for (int qi = 0; qi < 2; qi++) {
      if (qi == 0 && !act0) continue;
      const int qr = qrw[qi];
      const bool diag = (ti == lt[qi]);
      float pm[4] = {-3.0e38f, -3.0e38f, -3.0e38f, -3.0e38f};
      #pragma unroll
      for (int tf = 0; tf < 4; tf++)
        #pragma unroll
        for (int r = 0; r < 4; r++) {
          float sv = sf[qi][tf][r] * scale;
          if (diag && (t0 + tf * 16 + l15 > qr + lg * 4 + r)) sv = -3.0e38f;
          sf[qi][tf][r] = sv;
          pm[r] = fmaxf(pm[r], sv);
        }
      float corr[4];
      #pragma unroll
      for (int r = 0; r < 4; r++) {
        #pragma unroll
        for (int x = 1; x < 16; x <<= 1) pm[r] = fmaxf(pm[r], __shfl_xor(pm[r], x));
        const float nm = fmaxf(mr[qi][r], pm[r]);
        corr[r] = __expf(mr[qi][r] - nm);
        mr[qi][r] = nm;
      }
      float lsum[4] = {0.f, 0.f, 0.f, 0.f};
      #pragma unroll
      for (int tf = 0; tf < 4; tf++)
        #pragma unroll
        for (int r = 0; r < 4; r++) {
          const float p = __expf(sf[qi][tf][r] - mr[qi][r]);
          sf[qi][tf][r] = p;
          lsum[r] += p;
        }
      #pragma unroll
      for (int tf = 0; tf < 4; tf++)
        #pragma unroll
        for (int r = 0; r < 4; r++)
          Ps[wid][qi][(lg * 4 + r) * 72 + tf * 16 + l15] = __float2bfloat16(sf[qi][tf][r]);
      #pragma unroll
      for (int r = 0; r < 4; r++) {
        #pragma unroll
        for (int x = 1; x < 16; x <<= 1) lsum[r] += __shfl_xor(lsum[r], x);
        lr[qi][r] = lr[qi][r] * corr[r] + lsum[r];
      }
      #pragma unroll
      for (int hf = 0; hf < 2; hf++)
        #pragma unroll
        for (int r = 0; r < 4; r++) oacc[qi][hf][r] *= corr[r];

      __builtin_amdgcn_s_setprio(1);
      #pragma unroll
      for (int kt = 0; kt < 2; kt++) {
        const bf8v pv = *(const bf8v*)&Ps[wid][qi][l15 * 72 + kt * 32 + lg * 8];
        #pragma unroll
        for (int hf = 0; hf < 2; hf++)
          oacc[qi][hf] = MFMA(pv, vb[kt][hf], oacc[qi][hf]);
      }
      __builtin_amdgcn_s_setprio(0);
    }
  }

  #pragma unroll
  for (int qi = 0; qi < 2; qi++)
    #pragma unroll
    for (int hf = 0; hf < 2; hf++)
      #pragma unroll
      for (int r = 0; r < 4; r++)
        o[((size_t)bh * Ss + qrw[qi] + lg * 4 + r) * HDd + hf * 16 + l15] =
            __float2bfloat16(oacc[qi][hf][r] / lr[qi][r]);
}

extern "C" void kernel_launch(void* const* d_in, const int* in_sizes, int n_in,
                              void* d_out, int out_size, void* d_ws, size_t ws_size,
                              hipStream_t stream)
{
  const float* emb     = (const float*)d_in[0];
  const float* pos_emb = (const float*)d_in[1];
  const float* attn_w  = (const float*)d_in[2];
  const float* wq      = (const float*)d_in[3];
  const float* bq      = (const float*)d_in[4];
  const float* wk      = (const float*)d_in[5];
  const float* bk      = (const float*)d_in[6];
  const float* wv      = (const float*)d_in[7];
  const float* bv      = (const float*)d_in[8];
  const float* cos_t   = (const float*)d_in[9];
  const float* sin_t   = (const float*)d_in[10];
  const float* ffn_w   = (const float*)d_in[11];
  const float* w_gate  = (const float*)d_in[12];
  const float* b_gate  = (const float*)d_in[13];
  const float* w_up    = (const float*)d_in[14];
  const float* b_up    = (const float*)d_in[15];
  const float* w_down  = (const float*)d_in[16];
  const float* b_down  = (const float*)d_in[17];
  const int*   tok     = (const int*)d_in[18];
  float* out = (float*)d_out;

  const size_t NT = (size_t)Bb * Ss;   // 8192
  char* base = (char*)d_ws;
  size_t off = 0;
  auto alloc = [&](size_t bytes) {
    void* r = base + off;
    off = (off + bytes + 255) & ~(size_t)255;
    return r;
  };
  bf16*  h_bf   = (bf16*)alloc(NT * Dd * 2);
  bf16*  x_bf   = (bf16*)alloc(NT * Dd * 2);
  bf16*  q_bf   = (bf16*)alloc(NT * Dd * 2);
  bf16*  k_bf   = (bf16*)alloc(NT * HDd * 2);
  bf16*  vt_bf  = (bf16*)alloc(NT * Dd * 2);
  bf16*  o_bf   = (bf16*)alloc(NT * Dd * 2);
  bf16*  x2_bf  = (bf16*)alloc(NT * Dd * 2);
  bf16*  g_bf   = (bf16*)alloc(NT * (size_t)FKp * 2);
  bf16*  wqkv_b = (bf16*)alloc((size_t)640 * 256 * 2);
  bf16*  wgate_b= (bf16*)alloc((size_t)768 * 256 * 2);
  bf16*  wup_b  = (bf16*)alloc((size_t)768 * 256 * 2);
  bf16*  wdown_b= (bf16*)alloc((size_t)256 * FKp * 2);

  k_cvt_all<<<dim3(2880), 256, 0, stream>>>(
      wq, wk, wv, w_gate, w_up, w_down, wqkv_b, wgate_b, wup_b, wdown_b);

  k_embed_norm<<<dim3(NT), 256, 0, stream>>>(emb, pos_emb, tok, attn_w, h_bf, x_bf);

  k_qkv<<<dim3(NT / 128, 10), 256, 0, stream>>>(
      x_bf, wqkv_b, bq, bk, bv, cos_t, sin_t, q_bf, k_bf, vt_bf);

  k_attn_mfma<<<dim3(4, Hh, Bb), 256, 0, stream>>>(q_bf, k_bf, vt_bf, o_bf);

  k_add_norm<<<dim3(NT), 256, 0, stream>>>(o_bf, h_bf, ffn_w, x2_bf);

  k_ffn<<<dim3(NT / 128, 11), 256, 0, stream>>>(
      x2_bf, wgate_b, wup_b, b_gate, b_up, g_bf);

  k_down<<<dim3(NT / 64, 4), 256, 0, stream>>>(
      g_bf, wdown_b, b_down, x2_bf, out);
}

// Round 10
// 90.475 us; speedup vs baseline: 4.6810x; 1.0474x over previous
//
#include <hip/hip_runtime.h>
#include <hip/hip_bf16.h>
#include <cstddef>
#include <cstdint>

constexpr int Bb = 16, Ss = 512, Dd = 256, Hh = 8, HDd = 32, Ff = 682;
constexpr int FKp = 704;            // padded K for down GEMM (682 -> 704 = 11*64)
constexpr float EPSf = 1.1920928955078125e-07f;

typedef short bf8v __attribute__((ext_vector_type(8)));
typedef float f4 __attribute__((ext_vector_type(4)));
using bf16 = __hip_bfloat16;

__device__ inline f4 MFMA(bf8v a, bf8v b, f4 c) {
  return __builtin_amdgcn_mfma_f32_16x16x32_bf16(a, b, c, 0, 0, 0);
}

// ---------------- weight converts + embed+rmsnorm in ONE launch ----------------
// blocks 0..2879: weight cvt; blocks 2880..11071: embed+norm row = bx-2880
__global__ __launch_bounds__(256) void k_prep(
    const float* __restrict__ wq, const float* __restrict__ wk,
    const float* __restrict__ wv, const float* __restrict__ wg,
    const float* __restrict__ wu, const float* __restrict__ wd,
    bf16* __restrict__ dqkv, bf16* __restrict__ dgate,
    bf16* __restrict__ dup, bf16* __restrict__ ddown,
    const float* __restrict__ emb, const float* __restrict__ pos,
    const int* __restrict__ tok, const float* __restrict__ w,
    bf16* __restrict__ hb, bf16* __restrict__ xb)
{
  const int b = blockIdx.x, tid = threadIdx.x;
  if (b < 640) {
    const int idx = b * 256 + tid;
    const int row = idx >> 8, col = idx & 255;
    float v;
    if (row < 256)      v = wq[(size_t)row * 256 + col];
    else if (row < 288) v = wk[(size_t)(row - 256) * 256 + col];
    else if (row < 544) v = wv[(size_t)(row - 288) * 256 + col];
    else                v = 0.f;
    dqkv[idx] = __float2bfloat16(v);
  } else if (b < 2176) {
    const bool isg = b < 1408;
    const int idx = (b - (isg ? 640 : 1408)) * 256 + tid;
    const int row = idx >> 8, col = idx & 255;
    const float* src = isg ? wg : wu;
    float v = (row < Ff) ? src[(size_t)row * 256 + col] : 0.f;
    (isg ? dgate : dup)[idx] = __float2bfloat16(v);
  } else if (b < 2880) {
    const int idx = (b - 2176) * 256 + tid;   // over [256][704]
    const int row = idx / FKp, col = idx - row * FKp;
    float v = (col < Ff) ? wd[(size_t)row * Ff + col] : 0.f;
    ddown[idx] = __float2bfloat16(v);
  } else {
    const int row = b - 2880;
    const int s = row & (Ss - 1);
    const int t = tok[row];
    float v = emb[(size_t)t * Dd + tid] + pos[(size_t)s * Dd + tid];
    float ss = v * v;
    #pragma unroll
    for (int off = 32; off > 0; off >>= 1) ss += __shfl_down(ss, off);
    __shared__ float red[4];
    if ((tid & 63) == 0) red[tid >> 6] = ss;
    __syncthreads();
    const float tot = red[0] + red[1] + red[2] + red[3];
    const float r = rsqrtf(tot * (1.0f / Dd) + EPSf);
    const size_t o = (size_t)row * Dd + tid;
    hb[o] = __float2bfloat16(v);
    xb[o] = __float2bfloat16(v * r * w[tid]);
  }
}

// ---------------- residual add + rmsnorm -> x2_bf ----------------
__global__ __launch_bounds__(256) void k_add_norm(
    const bf16* __restrict__ a, const bf16* __restrict__ hb,
    const float* __restrict__ w, bf16* __restrict__ x2b)
{
  const int row = blockIdx.x;
  const int tid = threadIdx.x;
  const size_t off = (size_t)row * Dd + tid;
  const float v = __bfloat162float(a[off]) + __bfloat162float(hb[off]);
  float ss = v * v;
  #pragma unroll
  for (int o = 32; o > 0; o >>= 1) ss += __shfl_down(ss, o);
  __shared__ float red[4];
  if ((tid & 63) == 0) red[tid >> 6] = ss;
  __syncthreads();
  const float tot = red[0] + red[1] + red[2] + red[3];
  const float r = rsqrtf(tot * (1.0f / Dd) + EPSf);
  x2b[off] = __float2bfloat16(v * r * w[tid]);
}

// ---------------- qkv GEMM: BM=128 BN=64 K=256, rope epilogue, V transposed ----
__global__ __launch_bounds__(256) void k_qkv(
    const bf16* __restrict__ A, const bf16* __restrict__ W,
    const float* __restrict__ bias0, const float* __restrict__ bias1,
    const float* __restrict__ bias2,
    const float* __restrict__ cost, const float* __restrict__ sint,
    bf16* __restrict__ ob0, bf16* __restrict__ ob1, bf16* __restrict__ vt)
{
  __shared__ bf16 As[128 * 72];
  __shared__ bf16 Bs[64 * 72];
  const int tid = threadIdx.x, lane = tid & 63, wid = tid >> 6;
  const int l15 = lane & 15, lg = lane >> 4;
  const int m0 = blockIdx.x * 128, n0 = blockIdx.y * 64;
  const int wr = (wid >> 1) * 64, wc = (wid & 1) * 32;
  const int srow = tid >> 3, scol = (tid & 7) * 8;

  f4 acc[4][2];
  #pragma unroll
  for (int i = 0; i < 4; i++)
    #pragma unroll
    for (int j = 0; j < 2; j++) acc[i][j] = (f4){0.f, 0.f, 0.f, 0.f};

  bf8v pa[4], pb[2];
  #pragma unroll
  for (int i = 0; i < 4; i++)
    pa[i] = *(const bf8v*)&A[(size_t)(m0 + srow + i * 32) * 256 + scol];
  #pragma unroll
  for (int i = 0; i < 2; i++)
    pb[i] = *(const bf8v*)&W[(size_t)(n0 + srow + i * 32) * 256 + scol];
  #pragma unroll
  for (int i = 0; i < 4; i++) *(bf8v*)&As[(srow + i * 32) * 72 + scol] = pa[i];
  #pragma unroll
  for (int i = 0; i < 2; i++) *(bf8v*)&Bs[(srow + i * 32) * 72 + scol] = pb[i];
  __syncthreads();

  for (int ks = 0; ks < 4; ks++) {
    if (ks < 3) {
      const int kn = (ks + 1) * 64;
      #pragma unroll
      for (int i = 0; i < 4; i++)
        pa[i] = *(const bf8v*)&A[(size_t)(m0 + srow + i * 32) * 256 + kn + scol];
      #pragma unroll
      for (int i = 0; i < 2; i++)
        pb[i] = *(const bf8v*)&W[(size_t)(n0 + srow + i * 32) * 256 + kn + scol];
    }
    #pragma unroll
    for (int kk = 0; kk < 64; kk += 32) {
      bf8v af[4], bw[2];
      #pragma unroll
      for (int mi = 0; mi < 4; mi++)
        af[mi] = *(const bf8v*)&As[(wr + mi * 16 + l15) * 72 + kk + lg * 8];
      #pragma unroll
      for (int ni = 0; ni < 2; ni++)
        bw[ni] = *(const bf8v*)&Bs[(wc + ni * 16 + l15) * 72 + kk + lg * 8];
      #pragma unroll
      for (int mi = 0; mi < 4; mi++)
        #pragma unroll
        for (int ni = 0; ni < 2; ni++)
          acc[mi][ni] = MFMA(af[mi], bw[ni], acc[mi][ni]);
    }
    __syncthreads();
    if (ks < 3) {
      #pragma unroll
      for (int i = 0; i < 4; i++) *(bf8v*)&As[(srow + i * 32) * 72 + scol] = pa[i];
      #pragma unroll
      for (int i = 0; i < 2; i++) *(bf8v*)&Bs[(srow + i * 32) * 72 + scol] = pb[i];
      __syncthreads();
    }
  }

  #pragma unroll
  for (int mi = 0; mi < 4; mi++) {
    #pragma unroll
    for (int ni = 0; ni < 2; ni++) {
      const int nbase = n0 + wc + ni * 16;
      const int n = nbase + l15;
      if (nbase < 288) {                      // q or k region: rope
        #pragma unroll
        for (int r = 0; r < 4; r++) {
          const int m = m0 + wr + mi * 16 + lg * 4 + r;
          float vb2 = acc[mi][ni][r] + (nbase < 256 ? bias0[n] : bias1[n - 256]);
          int s, hd;
          if (nbase < 256) { const int flat = ((m & 511) << 8) + n; s = (flat >> 5) & 511; hd = n & 31; }
          else             { s = m & 511; hd = n - 256; }
          const float c = cost[s * 32 + hd], sn = sint[s * 32 + hd];
          const float other = __shfl_xor(vb2, 1);
          const float res = (n & 1) ? (other * sn + vb2 * c) : (vb2 * c - other * sn);
          if (nbase < 256) ob0[(size_t)m * 256 + n] = __float2bfloat16(res);
          else             ob1[(size_t)m * 32 + hd] = __float2bfloat16(res);
        }
      } else if (nbase < 544) {               // v region: transpose via C-order reshape
        const int rel = n - 288;              // feature col in vlin, 0..255
        const int hd = rel & 31, rq = rel >> 5;
        const int mb = m0 + wr + mi * 16 + lg * 4;   // base row, mult of 4
        const int b = mb >> 9;
        const float bv = bias2[rel];
        #pragma unroll
        for (int r = 0; r < 4; r++) {
          const int s = (mb + r) & 511;
          // v4[b][h][s4][hd] = vlin[b][s][rel]:  h = s>>6, s4 = (s&63)*8 + rq
          const int hh2 = s >> 6;
          const int s4 = ((s & 63) << 3) + rq;
          vt[((size_t)(b * Hh + hh2) * HDd + hd) * Ss + s4] =
              __float2bfloat16(acc[mi][ni][r] + bv);
        }
      }
    }
  }
}

// ---------------- fused FFN gate+up: BM=128 BN=64 -> g_bf [8192][704] ----
__global__ __launch_bounds__(256) void k_ffn(
    const bf16* __restrict__ A, const bf16* __restrict__ Wg,
    const bf16* __restrict__ Wu,
    const float* __restrict__ bg, const float* __restrict__ bu,
    bf16* __restrict__ out)
{
  __shared__ bf16 As[128 * 72];
  __shared__ bf16 Gs[64 * 72];
  __shared__ bf16 Us[64 * 72];
  const int tid = threadIdx.x, lane = tid & 63, wid = tid >> 6;
  const int l15 = lane & 15, lg = lane >> 4;
  const int m0 = blockIdx.x * 128, n0 = blockIdx.y * 64;
  const int wr = (wid >> 1) * 64, wc = (wid & 1) * 32;
  const int srow = tid >> 3, scol = (tid & 7) * 8;

  f4 accg[4][2], accu[4][2];
  #pragma unroll
  for (int i = 0; i < 4; i++)
    #pragma unroll
    for (int j = 0; j < 2; j++) {
      accg[i][j] = (f4){0.f, 0.f, 0.f, 0.f};
      accu[i][j] = (f4){0.f, 0.f, 0.f, 0.f};
    }

  bf8v pa[4], pg[2], pu[2];
  #pragma unroll
  for (int i = 0; i < 4; i++)
    pa[i] = *(const bf8v*)&A[(size_t)(m0 + srow + i * 32) * 256 + scol];
  #pragma unroll
  for (int i = 0; i < 2; i++) {
    pg[i] = *(const bf8v*)&Wg[(size_t)(n0 + srow + i * 32) * 256 + scol];
    pu[i] = *(const bf8v*)&Wu[(size_t)(n0 + srow + i * 32) * 256 + scol];
  }
  #pragma unroll
  for (int i = 0; i < 4; i++) *(bf8v*)&As[(srow + i * 32) * 72 + scol] = pa[i];
  #pragma unroll
  for (int i = 0; i < 2; i++) {
    *(bf8v*)&Gs[(srow + i * 32) * 72 + scol] = pg[i];
    *(bf8v*)&Us[(srow + i * 32) * 72 + scol] = pu[i];
  }
  __syncthreads();

  for (int ks = 0; ks < 4; ks++) {
    if (ks < 3) {
      const int kn = (ks + 1) * 64;
      #pragma unroll
      for (int i = 0; i < 4; i++)
        pa[i] = *(const bf8v*)&A[(size_t)(m0 + srow + i * 32) * 256 + kn + scol];
      #pragma unroll
      for (int i = 0; i < 2; i++) {
        pg[i] = *(const bf8v*)&Wg[(size_t)(n0 + srow + i * 32) * 256 + kn + scol];
        pu[i] = *(const bf8v*)&Wu[(size_t)(n0 + srow + i * 32) * 256 + kn + scol];
      }
    }
    #pragma unroll
    for (int kk = 0; kk < 64; kk += 32) {
      bf8v af[4], bgf[2], buf[2];
      #pragma unroll
      for (int mi = 0; mi < 4; mi++)
        af[mi] = *(const bf8v*)&As[(wr + mi * 16 + l15) * 72 + kk + lg * 8];
      #pragma unroll
      for (int ni = 0; ni < 2; ni++) {
        bgf[ni] = *(const bf8v*)&Gs[(wc + ni * 16 + l15) * 72 + kk + lg * 8];
        buf[ni] = *(const bf8v*)&Us[(wc + ni * 16 + l15) * 72 + kk + lg * 8];
      }
      #pragma unroll
      for (int mi = 0; mi < 4; mi++)
        #pragma unroll
        for (int ni = 0; ni < 2; ni++) {
          accg[mi][ni] = MFMA(af[mi], bgf[ni], accg[mi][ni]);
          accu[mi][ni] = MFMA(af[mi], buf[ni], accu[mi][ni]);
        }
    }
    __syncthreads();
    if (ks < 3) {
      #pragma unroll
      for (int i = 0; i < 4; i++) *(bf8v*)&As[(srow + i * 32) * 72 + scol] = pa[i];
      #pragma unroll
      for (int i = 0; i < 2; i++) {
        *(bf8v*)&Gs[(srow + i * 32) * 72 + scol] = pg[i];
        *(bf8v*)&Us[(srow + i * 32) * 72 + scol] = pu[i];
      }
      __syncthreads();
    }
  }

  #pragma unroll
  for (int ni = 0; ni < 2; ni++) {
    const int n = n0 + wc + ni * 16 + l15;
    const float bgv = (n < Ff) ? bg[n] : 0.f;
    const float buv = (n < Ff) ? bu[n] : 0.f;
    #pragma unroll
    for (int mi = 0; mi < 4; mi++) {
      #pragma unroll
      for (int r = 0; r < 4; r++) {
        const int m = m0 + wr + mi * 16 + lg * 4 + r;
        float res = 0.f;
        if (n < Ff) {
          const float gv = accg[mi][ni][r] + bgv;
          const float uv = accu[mi][ni][r] + buv;
          res = gv / (1.f + __expf(-gv)) * uv;
        }
        out[(size_t)m * FKp + n] = __float2bfloat16(res);
      }
    }
  }
}

// ---------------- down GEMM: BM=64 BN=64 K=704, +bias +resid(bf16) -> out f32 ----
__global__ __launch_bounds__(256) void k_down(
    const bf16* __restrict__ A, const bf16* __restrict__ W,
    const float* __restrict__ bias, const bf16* __restrict__ resid,
    float* __restrict__ out)
{
  __shared__ bf16 As[64 * 72];
  __shared__ bf16 Bs[64 * 72];
  const int tid = threadIdx.x, lane = tid & 63, wid = tid >> 6;
  const int l15 = lane & 15, lg = lane >> 4;
  const int m0 = blockIdx.x * 64, n0 = blockIdx.y * 64;
  const int wr = (wid >> 1) * 32, wc = (wid & 1) * 32;
  const int srow = tid >> 3, scol = (tid & 7) * 8;

  f4 acc[2][2];
  #pragma unroll
  for (int i = 0; i < 2; i++)
    #pragma unroll
    for (int j = 0; j < 2; j++) acc[i][j] = (f4){0.f, 0.f, 0.f, 0.f};

  bf8v pa[2], pb[2];
  #pragma unroll
  for (int i = 0; i < 2; i++) {
    pa[i] = *(const bf8v*)&A[(size_t)(m0 + srow + i * 32) * FKp + scol];
    pb[i] = *(const bf8v*)&W[(size_t)(n0 + srow + i * 32) * FKp + scol];
  }
  #pragma unroll
  for (int i = 0; i < 2; i++) {
    *(bf8v*)&As[(srow + i * 32) * 72 + scol] = pa[i];
    *(bf8v*)&Bs[(srow + i * 32) * 72 + scol] = pb[i];
  }
  __syncthreads();

  for (int ks = 0; ks < 11; ks++) {
    if (ks < 10) {
      const int kn = (ks + 1) * 64;
      #pragma unroll
      for (int i = 0; i < 2; i++) {
        pa[i] = *(const bf8v*)&A[(size_t)(m0 + srow + i * 32) * FKp + kn + scol];
        pb[i] = *(const bf8v*)&W[(size_t)(n0 + srow + i * 32) * FKp + kn + scol];
      }
    }
    #pragma unroll
    for (int kk = 0; kk < 64; kk += 32) {
      bf8v af[2], bw[2];
      #pragma unroll
      for (int mi = 0; mi < 2; mi++)
        af[mi] = *(const bf8v*)&As[(wr + mi * 16 + l15) * 72 + kk + lg * 8];
      #pragma unroll
      for (int ni = 0; ni < 2; ni++)
        bw[ni] = *(const bf8v*)&Bs[(wc + ni * 16 + l15) * 72 + kk + lg * 8];
      #pragma unroll
      for (int mi = 0; mi < 2; mi++)
        #pragma unroll
        for (int ni = 0; ni < 2; ni++)
          acc[mi][ni] = MFMA(af[mi], bw[ni], acc[mi][ni]);
    }
    __syncthreads();
    if (ks < 10) {
      #pragma unroll
      for (int i = 0; i < 2; i++) {
        *(bf8v*)&As[(srow + i * 32) * 72 + scol] = pa[i];
        *(bf8v*)&Bs[(srow + i * 32) * 72 + scol] = pb[i];
      }
      __syncthreads();
    }
  }

  #pragma unroll
  for (int ni = 0; ni < 2; ni++) {
    const int n = n0 + wc + ni * 16 + l15;
    const float bv = bias[n];
    #pragma unroll
    for (int mi = 0; mi < 2; mi++) {
      #pragma unroll
      for (int r = 0; r < 4; r++) {
        const int m = m0 + wr + mi * 16 + lg * 4 + r;
        out[(size_t)m * 256 + n] = acc[mi][ni][r] + bv +
            __bfloat162float(resid[(size_t)m * 256 + n]);
      }
    }
  }
}

// ---------------- MFMA flash attention: swapped QK^T, 1 wave = 1 q-fragment ----
// grid (32, H, B), 64 threads. Wave owns q-rows [(31-bx)*16, +16).
// Swapped mfma(K,Q): lane holds S[t=tf*16+lg*4+r][q=l15] -> row-reduce = 2 shfl.
__global__ __launch_bounds__(64) void k_attn_mfma(
    const bf16* __restrict__ q, const bf16* __restrict__ k,
    const bf16* __restrict__ vt, bf16* __restrict__ o)
{
  __shared__ bf16 Ps[16 * 72];         // [q16][72 pad] = 2.3 KB
  const int lane = threadIdx.x;
  const int l15 = lane & 15, lg = lane >> 4;
  const int hh = blockIdx.y, bb = blockIdx.z;
  const int bh = bb * Hh + hh;
  const int qrow = (31 - blockIdx.x) * 16;   // longest blocks dispatch first
  const int lt = (qrow + 15) >> 6;
  const float scale = 0.17677669529663687f;

  const bf16* kg = k + (size_t)bb * Ss * HDd;
  const bf16* vg = vt + (size_t)bh * (Ss * HDd);

  // B-operand Q fragment: lane holds Q[q=l15][d=lg*8..+7]
  const bf8v qf = *(const bf8v*)&q[((size_t)bh * Ss + qrow + l15) * HDd + lg * 8];

  f4 oacc[2];
  oacc[0] = (f4){0.f, 0.f, 0.f, 0.f};
  oacc[1] = (f4){0.f, 0.f, 0.f, 0.f};
  float m = -3.0e38f, l = 0.f;

  for (int ti = 0; ti <= lt; ti++) {
    const int t0 = ti * 64;

    // QK^T swapped: A = K rows t, B = Q cols q
    f4 sf[4];
    __builtin_amdgcn_s_setprio(1);
    #pragma unroll
    for (int tf = 0; tf < 4; tf++) {
      const bf8v kf = *(const bf8v*)&kg[(size_t)(t0 + tf * 16 + l15) * HDd + lg * 8];
      sf[tf] = MFMA(kf, qf, (f4){0.f, 0.f, 0.f, 0.f});
    }
    __builtin_amdgcn_s_setprio(0);

    // prefetch V fragments (latency hides under softmax)
    bf8v vb[2][2];
    #pragma unroll
    for (int kt = 0; kt < 2; kt++)
      #pragma unroll
      for (int hf = 0; hf < 2; hf++)
        vb[kt][hf] = *(const bf8v*)&vg[(size_t)(hf * 16 + l15) * Ss + t0 + kt * 32 + lg * 8];

    // scale + causal mask; lane holds 16 t-values for q = qrow + l15
    float pm = -3.0e38f;
    if (ti == lt) {
      #pragma unroll
      for (int tf = 0; tf < 4; tf++)
        #pragma unroll
        for (int r = 0; r < 4; r++) {
          float sv = sf[tf][r] * scale;
          if (t0 + tf * 16 + lg * 4 + r > qrow + l15) sv = -3.0e38f;
          sf[tf][r] = sv;
          pm = fmaxf(pm, sv);
        }
    } else {
      #pragma unroll
      for (int tf = 0; tf < 4; tf++)
        #pragma unroll
        for (int r = 0; r < 4; r++) {
          const float sv = sf[tf][r] * scale;
          sf[tf][r] = sv;
          pm = fmaxf(pm, sv);
        }
    }
    pm = fmaxf(pm, __shfl_xor(pm, 16));
    pm = fmaxf(pm, __shfl_xor(pm, 32));

    const float nm = fmaxf(m, pm);
    const float corr = __expf(m - nm);
    m = nm;

    float ls = 0.f;
    #pragma unroll
    for (int tf = 0; tf < 4; tf++)
      #pragma unroll
      for (int r = 0; r < 4; r++) {
        const float p = __expf(sf[tf][r] - m);
        sf[tf][r] = p;
        ls += p;
      }
    ls += __shfl_xor(ls, 16);
    ls += __shfl_xor(ls, 32);
    l = l * corr + ls;

    // write P: lane holds P[t=tf*16+lg*4+r][q=l15] -> Ps[q][t], 4 packed bf16
    #pragma unroll
    for (int tf = 0; tf < 4; tf++) {
      bf16 t4[4];
      #pragma unroll
      for (int r = 0; r < 4; r++) t4[r] = __float2bfloat16(sf[tf][r]);
      *(uint2*)&Ps[l15 * 72 + tf * 16 + lg * 4] = *(const uint2*)t4;
    }

    // rescale oacc: corr is q=l15-indexed; oacc rows are q=lg*4+r
    float corrT[4];
    #pragma unroll
    for (int r = 0; r < 4; r++) corrT[r] = __shfl(corr, lg * 4 + r);
    #pragma unroll
    for (int hf = 0; hf < 2; hf++)
      #pragma unroll
      for (int r = 0; r < 4; r++) oacc[hf][r] *= corrT[r];

    // PV: A = P[q][t] from LDS, B = V^T
    __builtin_amdgcn_s_setprio(1);
    #pragma unroll
    for (int kt = 0; kt < 2; kt++) {
      const bf8v pv = *(const bf8v*)&Ps[l15 * 72 + kt * 32 + lg * 8];
      #pragma unroll
      for (int hf = 0; hf < 2; hf++)
        oacc[hf] = MFMA(pv, vb[kt][hf], oacc[hf]);
    }
    __builtin_amdgcn_s_setprio(0);
  }

  float lT[4];
  #pragma unroll
  for (int r = 0; r < 4; r++) lT[r] = __shfl(l, lg * 4 + r);
  #pragma unroll
  for (int hf = 0; hf < 2; hf++)
    #pragma unroll
    for (int r = 0; r < 4; r++)
      o[((size_t)bh * Ss + qrow + lg * 4 + r) * HDd + hf * 16 + l15] =
          __float2bfloat16(oacc[hf][r] / lT[r]);
}

extern "C" void kernel_launch(void* const* d_in, const int* in_sizes, int n_in,
                              void* d_out, int out_size, void* d_ws, size_t ws_size,
                              hipStream_t stream)
{
  const float* emb     = (const float*)d_in[0];
  const float* pos_emb = (const float*)d_in[1];
  const float* attn_w  = (const float*)d_in[2];
  const float* wq      = (const float*)d_in[3];
  const float* bq      = (const float*)d_in[4];
  const float* wk      = (const float*)d_in[5];
  const float* bk      = (const float*)d_in[6];
  const float* wv      = (const float*)d_in[7];
  const float* bv      = (const float*)d_in[8];
  const float* cos_t   = (const float*)d_in[9];
  const float* sin_t   = (const float*)d_in[10];
  const float* ffn_w   = (const float*)d_in[11];
  const float* w_gate  = (const float*)d_in[12];
  const float* b_gate  = (const float*)d_in[13];
  const float* w_up    = (const float*)d_in[14];
  const float* b_up    = (const float*)d_in[15];
  const float* w_down  = (const float*)d_in[16];
  const float* b_down  = (const float*)d_in[17];
  const int*   tok     = (const int*)d_in[18];
  float* out = (float*)d_out;

  const size_t NT = (size_t)Bb * Ss;   // 8192
  char* base = (char*)d_ws;
  size_t off = 0;
  auto alloc = [&](size_t bytes) {
    void* r = base + off;
    off = (off + bytes + 255) & ~(size_t)255;
    return r;
  };
  bf16*  h_bf   = (bf16*)alloc(NT * Dd * 2);
  bf16*  x_bf   = (bf16*)alloc(NT * Dd * 2);
  bf16*  q_bf   = (bf16*)alloc(NT * Dd * 2);
  bf16*  k_bf   = (bf16*)alloc(NT * HDd * 2);
  bf16*  vt_bf  = (bf16*)alloc(NT * Dd * 2);
  bf16*  o_bf   = (bf16*)alloc(NT * Dd * 2);
  bf16*  x2_bf  = (bf16*)alloc(NT * Dd * 2);
  bf16*  g_bf   = (bf16*)alloc(NT * (size_t)FKp * 2);
  bf16*  wqkv_b = (bf16*)alloc((size_t)640 * 256 * 2);
  bf16*  wgate_b= (bf16*)alloc((size_t)768 * 256 * 2);
  bf16*  wup_b  = (bf16*)alloc((size_t)768 * 256 * 2);
  bf16*  wdown_b= (bf16*)alloc((size_t)256 * FKp * 2);

  k_prep<<<dim3(2880 + NT), 256, 0, stream>>>(
      wq, wk, wv, w_gate, w_up, w_down, wqkv_b, wgate_b, wup_b, wdown_b,
      emb, pos_emb, tok, attn_w, h_bf, x_bf);

  k_qkv<<<dim3(NT / 128, 10), 256, 0, stream>>>(
      x_bf, wqkv_b, bq, bk, bv, cos_t, sin_t, q_bf, k_bf, vt_bf);

  k_attn_mfma<<<dim3(32, Hh, Bb), 64, 0, stream>>>(q_bf, k_bf, vt_bf, o_bf);

  k_add_norm<<<dim3(NT), 256, 0, stream>>>(o_bf, h_bf, ffn_w, x2_bf);

  k_ffn<<<dim3(NT / 128, 11), 256, 0, stream>>>(
      x2_bf, wgate_b, wup_b, b_gate, b_up, g_bf);

  k_down<<<dim3(NT / 64, 4), 256, 0, stream>>>(
      g_bf, wdown_b, b_down, x2_bf, out);
}